// Round 4
// baseline (69795.581 us; speedup 1.0000x reference)
//
#include <hip/hip_runtime.h>
#include <hip/hip_bf16.h>

typedef __bf16 bf16x8 __attribute__((ext_vector_type(8)));
typedef float  f32x4  __attribute__((ext_vector_type(4)));

#define B_ 32
#define S_ 512
#define I_ 256
#define H_ 1024
#define O_ 256
#define M_ (B_*S_)   // 16384
#define OUT_ELEMS ((size_t)B_*S_*O_)   // 4194304
#define NBLK 128

// ---------------- elementwise converts ----------------
__global__ void cvt_f32_bf16(const float* __restrict__ src, __hip_bfloat16* __restrict__ dst, int n) {
  for (int i = blockIdx.x*blockDim.x + threadIdx.x; i < n; i += gridDim.x*blockDim.x)
    dst[i] = __float2bfloat16(src[i]);
}

// x [B][S][I] f32 -> xb [S][B][I] bf16
__global__ void xpose_x(const float* __restrict__ x, __hip_bfloat16* __restrict__ xb) {
  const int total = B_*S_*I_;
  for (int d = blockIdx.x*blockDim.x + threadIdx.x; d < total; d += gridDim.x*blockDim.x) {
    int i = d & (I_-1);
    int b = (d >> 8) & (B_-1);
    int s = d >> 13;
    xb[d] = __float2bfloat16(x[((size_t)b*S_ + s)*I_ + i]);
  }
}

// ---------------- GEMM: C[M][N] = A[M][K] * W[N][K]^T ----------------
// MODE 0: store bf16 to dstb[gate][m][h] (gate = n>>10).
// MODE 1: store f32 out[(b*S+s)*O + n] = v + bias[n], m = s*32+b.
template<int MODE>
__global__ __launch_bounds__(256) void gemm_bf16(
    const __hip_bfloat16* __restrict__ A,
    const __hip_bfloat16* __restrict__ W,
    __hip_bfloat16* __restrict__ dstb,
    float* __restrict__ dstf,
    const float* __restrict__ bias,
    int K)
{
  // unpadded stride-32 (64B rows, 16B-aligned for b128) — m93/m97 layout
  __shared__ __hip_bfloat16 As[128][32];
  __shared__ __hip_bfloat16 Ws[64][32];
  const int tid  = threadIdx.x;
  const int wid  = tid >> 6, lane = tid & 63;
  const int m0   = blockIdx.y * 128, n0 = blockIdx.x * 64;
  const int col  = lane & 15, kl = (lane >> 4) * 8;
  const int lrow = tid >> 2, lcol = (tid & 3) * 8;
  f32x4 acc[2][4] = {};

  for (int k0 = 0; k0 < K; k0 += 32) {
    __syncthreads();
    *(bf16x8*)&As[lrow][lcol]    = *(const bf16x8*)&A[(size_t)(m0+lrow)*K    + k0 + lcol];
    *(bf16x8*)&As[lrow+64][lcol] = *(const bf16x8*)&A[(size_t)(m0+lrow+64)*K + k0 + lcol];
    *(bf16x8*)&Ws[lrow][lcol]    = *(const bf16x8*)&W[(size_t)(n0+lrow)*K    + k0 + lcol];
    __syncthreads();
    bf16x8 a0 = *(const bf16x8*)&As[wid*32 + col][kl];
    bf16x8 a1 = *(const bf16x8*)&As[wid*32 + 16 + col][kl];
#pragma unroll
    for (int nt = 0; nt < 4; ++nt) {
      bf16x8 bw = *(const bf16x8*)&Ws[nt*16 + col][kl];
      acc[0][nt] = __builtin_amdgcn_mfma_f32_16x16x32_bf16(a0, bw, acc[0][nt], 0, 0, 0);
      acc[1][nt] = __builtin_amdgcn_mfma_f32_16x16x32_bf16(a1, bw, acc[1][nt], 0, 0, 0);
    }
  }
#pragma unroll
  for (int mt = 0; mt < 2; ++mt)
#pragma unroll
    for (int nt = 0; nt < 4; ++nt)
#pragma unroll
      for (int j = 0; j < 4; ++j) {
        int m = m0 + wid*32 + mt*16 + (lane>>4)*4 + j;
        int n = n0 + nt*16 + col;
        float v = acc[mt][nt][j];
        if (MODE == 0) {
          int gate = n >> 10, h = n & 1023;
          dstb[(size_t)gate*((size_t)M_*H_) + (size_t)m*H_ + h] = __float2bfloat16(v);
        } else {
          int s = m >> 5, b = m & 31;
          dstf[((size_t)b*S_ + s)*O_ + n] = v + bias[n];
        }
      }
}

// ---------------- grid barrier (no cooperative launch) ----------------
// Monotonic generation counter: each of the NBLK blocks arrives once per call;
// call #i completes when count reaches i*NBLK. Counter zeroed by memsetAsync
// in kernel_launch (captured), so every launch/replay starts fresh.
__device__ __forceinline__ void gridbar(unsigned int* cnt, unsigned int target) {
  __threadfence();                 // release: make prior global writes visible
  __syncthreads();
  if (threadIdx.x == 0) {
    __hip_atomic_fetch_add(cnt, 1u, __ATOMIC_RELEASE, __HIP_MEMORY_SCOPE_AGENT);
    while (__hip_atomic_load(cnt, __ATOMIC_ACQUIRE, __HIP_MEMORY_SCOPE_AGENT) < target)
      __builtin_amdgcn_s_sleep(2);
  }
  __syncthreads();
  __threadfence();                 // acquire: invalidate stale cache
}

// ---------------- persistent recurrence ----------------
struct RecurArgs {
  const __hip_bfloat16 *xz, *xr, *xg;  // [S][B][H] bf16
  const __hip_bfloat16 *W2;            // [3*H][H] bf16: z rows 0..1023, r 1024..2047, g 2048..3071
  const float *bz, *br, *bg;           // [H]
  const float *h0;                     // initial h, stride 2*H per b
  float *h;                            // [B][H] f32
  __hip_bfloat16 *hb;                  // [B][H] bf16 mirror
  float *zbuf;                         // [B][H] f32
  __hip_bfloat16 *hrb;                 // [B][H] bf16 (h*r)
  __hip_bfloat16 *hs;                  // [S][B][H] bf16
  float *fin;                          // d_out hidden slot, stride 2*H per b
  unsigned int *bar;                   // barrier counter (zeroed)
};

__global__ __launch_bounds__(256) void recur(RecurArgs a) {
  __shared__ f32x4 part[8][64];     // [wave*2+mt][lane]
  const int tid  = threadIdx.x, wid = tid >> 6, lane = tid & 63;
  const int col  = lane & 15, kl = (lane >> 4) * 8;
  const int blk  = blockIdx.x;      // 0..127
  unsigned int tgt = 0;

  // init h from h0
  {
    int i = blk*256 + tid;          // exactly 32768 threads
    int b = i >> 10, hh = i & 1023;
    float v = a.h0[(size_t)b*2048 + hh];
    a.h[i] = v;
    a.hb[i] = __float2bfloat16(v);
  }
  tgt += NBLK; gridbar(a.bar, tgt);

  for (int t = 0; t < S_; ++t) {
    const __hip_bfloat16* xzt = a.xz + (size_t)t*(B_*H_);
    const __hip_bfloat16* xrt = a.xr + (size_t)t*(B_*H_);
    const __hip_bfloat16* xgt = a.xg + (size_t)t*(B_*H_);

    // ---- phase A: z (blocks 0..63) and r (blocks 64..127) pre-activations
    {
      const int npk = blk*16 + col;                       // packed W2 row, 0..2047
      const __hip_bfloat16* wr  = a.W2 + (size_t)npk*H_      + wid*256 + kl;
      const __hip_bfloat16* h0p = a.hb + (size_t)col*H_      + wid*256 + kl;
      const __hip_bfloat16* h1p = a.hb + (size_t)(col+16)*H_ + wid*256 + kl;
      f32x4 ac0 = {0.f,0.f,0.f,0.f}, ac1 = {0.f,0.f,0.f,0.f};
#pragma unroll
      for (int kc = 0; kc < 8; ++kc) {
        bf16x8 bw = *(const bf16x8*)(wr  + kc*32);
        bf16x8 a0 = *(const bf16x8*)(h0p + kc*32);
        bf16x8 a1 = *(const bf16x8*)(h1p + kc*32);
        ac0 = __builtin_amdgcn_mfma_f32_16x16x32_bf16(a0, bw, ac0, 0, 0, 0);
        ac1 = __builtin_amdgcn_mfma_f32_16x16x32_bf16(a1, bw, ac1, 0, 0, 0);
      }
      part[wid*2+0][lane] = ac0;
      part[wid*2+1][lane] = ac1;
    }
    __syncthreads();
    if (wid < 2) {
      const int mt = wid;
      f32x4 s4 = part[mt][lane];
      s4 += part[2+mt][lane]; s4 += part[4+mt][lane]; s4 += part[6+mt][lane];
      const int npk  = blk*16 + col;
      const int gate = blk >> 6;                          // 0=z, 1=r
      const int hh   = npk & 1023;
      const float bias = (gate == 0 ? a.bz : a.br)[hh];
      const __hip_bfloat16* xv = (gate == 0 ? xzt : xrt);
#pragma unroll
      for (int j = 0; j < 4; ++j) {
        int b = mt*16 + (lane>>4)*4 + j;
        float pre = s4[j] + __bfloat162float(xv[(size_t)b*H_ + hh]) + bias;
        float sg = 1.f / (1.f + __expf(-pre));
        if (gate == 0) {
          a.zbuf[(size_t)b*H_ + hh] = sg;
        } else {
          float hv = a.h[(size_t)b*H_ + hh];
          a.hrb[(size_t)b*H_ + hh] = __float2bfloat16(sg * hv);
        }
      }
    }
    tgt += NBLK; gridbar(a.bar, tgt);

    // ---- phase B: g pre-activation + h update (blocks 0..63)
    if (blk < 64) {
      {
        const int npk = 2048 + blk*16 + col;
        const __hip_bfloat16* wr  = a.W2  + (size_t)npk*H_      + wid*256 + kl;
        const __hip_bfloat16* h0p = a.hrb + (size_t)col*H_      + wid*256 + kl;
        const __hip_bfloat16* h1p = a.hrb + (size_t)(col+16)*H_ + wid*256 + kl;
        f32x4 ac0 = {0.f,0.f,0.f,0.f}, ac1 = {0.f,0.f,0.f,0.f};
#pragma unroll
        for (int kc = 0; kc < 8; ++kc) {
          bf16x8 bw = *(const bf16x8*)(wr  + kc*32);
          bf16x8 a0 = *(const bf16x8*)(h0p + kc*32);
          bf16x8 a1 = *(const bf16x8*)(h1p + kc*32);
          ac0 = __builtin_amdgcn_mfma_f32_16x16x32_bf16(a0, bw, ac0, 0, 0, 0);
          ac1 = __builtin_amdgcn_mfma_f32_16x16x32_bf16(a1, bw, ac1, 0, 0, 0);
        }
        part[wid*2+0][lane] = ac0;
        part[wid*2+1][lane] = ac1;
      }
      __syncthreads();
      if (wid < 2) {
        const int mt = wid;
        f32x4 s4 = part[mt][lane];
        s4 += part[2+mt][lane]; s4 += part[4+mt][lane]; s4 += part[6+mt][lane];
        const int hh = blk*16 + col;
        const float bias = a.bg[hh];
#pragma unroll
        for (int j = 0; j < 4; ++j) {
          int b = mt*16 + (lane>>4)*4 + j;
          float pre = s4[j] + __bfloat162float(xgt[(size_t)b*H_ + hh]) + bias;
          float g  = tanhf(pre);
          float z  = a.zbuf[(size_t)b*H_ + hh];
          float hv = a.h[(size_t)b*H_ + hh];
          float hn = z*hv + (1.f - z)*g;
          a.h[(size_t)b*H_ + hh]  = hn;
          a.hb[(size_t)b*H_ + hh] = __float2bfloat16(hn);
          a.hs[((size_t)t*B_ + b)*H_ + hh] = __float2bfloat16(hn);
          if (t == S_-2) a.fin[(size_t)b*2048 + hh] = hn;
        }
      }
    }
    tgt += NBLK; gridbar(a.bar, tgt);
  }
}

// ---------------- host ----------------
extern "C" void kernel_launch(void* const* d_in, const int* in_sizes, int n_in,
                              void* d_out, int out_size, void* d_ws, size_t ws_size,
                              hipStream_t stream) {
  (void)in_sizes; (void)n_in; (void)out_size; (void)ws_size;
  const float* x     = (const float*)d_in[0];
  const float* hid0  = (const float*)d_in[1];
  const float* z1_0  = (const float*)d_in[2];
  const float* z2_0  = (const float*)d_in[3];
  const float* z2b_0 = (const float*)d_in[4];
  const float* r1_0  = (const float*)d_in[5];
  const float* r2_0  = (const float*)d_in[6];
  const float* r2b_0 = (const float*)d_in[7];
  const float* g1_0  = (const float*)d_in[8];
  const float* g2_0  = (const float*)d_in[9];
  const float* g2b_0 = (const float*)d_in[10];
  const float* z1_1  = (const float*)d_in[11];
  const float* z2_1  = (const float*)d_in[12];
  const float* z2b_1 = (const float*)d_in[13];
  const float* r1_1  = (const float*)d_in[14];
  const float* r2_1  = (const float*)d_in[15];
  const float* r2b_1 = (const float*)d_in[16];
  const float* g1_1  = (const float*)d_in[17];
  const float* g2_1  = (const float*)d_in[18];
  const float* g2b_1 = (const float*)d_in[19];
  const float* Yw    = (const float*)d_in[20];
  const float* Yb    = (const float*)d_in[21];
  float* out = (float*)d_out;

  char* ws = (char*)d_ws;
  size_t off = 0;
  auto alloc = [&](size_t bytes) -> void* {
    void* p = ws + off; off += (bytes + 255) & ~(size_t)255; return p;
  };
  __hip_bfloat16* xproj = (__hip_bfloat16*)alloc((size_t)3*M_*H_*2);  // 96 MB
  __hip_bfloat16* hs    = (__hip_bfloat16*)alloc((size_t)M_*H_*2);    // 32 MB (layer0 out, then layer1 out)
  __hip_bfloat16* xb    = (__hip_bfloat16*)alloc((size_t)M_*I_*2);
  __hip_bfloat16* w1p0  = (__hip_bfloat16*)alloc((size_t)3*H_*I_*2);
  __hip_bfloat16* w1p1  = (__hip_bfloat16*)alloc((size_t)3*H_*H_*2);
  __hip_bfloat16* w2p0  = (__hip_bfloat16*)alloc((size_t)3*H_*H_*2);
  __hip_bfloat16* w2p1  = (__hip_bfloat16*)alloc((size_t)3*H_*H_*2);
  __hip_bfloat16* ywp   = (__hip_bfloat16*)alloc((size_t)O_*H_*2);
  float*          hcur  = (float*)         alloc((size_t)B_*H_*sizeof(float));
  __hip_bfloat16* hbc   = (__hip_bfloat16*)alloc((size_t)B_*H_*2);
  float*          zbuf  = (float*)         alloc((size_t)B_*H_*sizeof(float));
  __hip_bfloat16* hrb   = (__hip_bfloat16*)alloc((size_t)B_*H_*2);
  unsigned int*   bars  = (unsigned int*)  alloc(512);   // bar0 @ +0, bar1 @ +64 uints

  // zero barrier counters (captured into the graph -> fresh every replay)
  hipMemsetAsync(bars, 0, 512, stream);

  // converts / packing
  hipLaunchKernelGGL(xpose_x, dim3(2048), dim3(256), 0, stream, x, xb);
  auto CVT = [&](const float* s, __hip_bfloat16* d, int n) {
    hipLaunchKernelGGL(cvt_f32_bf16, dim3(512), dim3(256), 0, stream, s, d, n);
  };
  CVT(z1_0, w1p0,            H_*I_);
  CVT(r1_0, w1p0 + H_*I_,    H_*I_);
  CVT(g1_0, w1p0 + 2*H_*I_,  H_*I_);
  CVT(z2_0, w2p0,            H_*H_);
  CVT(r2_0, w2p0 + H_*H_,    H_*H_);
  CVT(g2_0, w2p0 + 2*H_*H_,  H_*H_);
  CVT(z1_1, w1p1,            H_*H_);
  CVT(r1_1, w1p1 + H_*H_,    H_*H_);
  CVT(g1_1, w1p1 + 2*H_*H_,  H_*H_);
  CVT(z2_1, w2p1,            H_*H_);
  CVT(r2_1, w2p1 + H_*H_,    H_*H_);
  CVT(g2_1, w2p1 + 2*H_*H_,  H_*H_);
  CVT(Yw,   ywp,             O_*H_);

  // layer 0 input projections: [S*B][3072] from K=256 -> bf16 xproj
  hipLaunchKernelGGL(gemm_bf16<0>, dim3(48, 128), dim3(256), 0, stream,
                     xb, w1p0, xproj, (float*)nullptr, (const float*)nullptr, I_);

  // layer 0 recurrence
  RecurArgs ra;
  ra.xz = xproj;
  ra.xr = xproj + (size_t)M_*H_;
  ra.xg = xproj + (size_t)2*M_*H_;
  ra.W2 = w2p0; ra.bz = z2b_0; ra.br = r2b_0; ra.bg = g2b_0;
  ra.h0 = hid0;                      // l = 0
  ra.h = hcur; ra.hb = hbc; ra.zbuf = zbuf; ra.hrb = hrb;
  ra.hs = hs;
  ra.fin = out + OUT_ELEMS;          // hidden[b][0][h]
  ra.bar = bars;
  hipLaunchKernelGGL(recur, dim3(NBLK), dim3(256), 0, stream, ra);

  // layer 1 input projections: A = hs (layer-0 outputs), K = 1024 -> bf16 xproj
  hipLaunchKernelGGL(gemm_bf16<0>, dim3(48, 128), dim3(256), 0, stream,
                     hs, w1p1, xproj, (float*)nullptr, (const float*)nullptr, H_);

  // layer 1 recurrence (hs reused for layer-1 outputs)
  ra.W2 = w2p1; ra.bz = z2b_1; ra.br = r2b_1; ra.bg = g2b_1;
  ra.h0 = hid0 + 1024;               // l = 1
  ra.hs = hs;
  ra.fin = out + OUT_ELEMS + 1024;   // hidden[b][1][h]
  ra.bar = bars + 64;
  hipLaunchKernelGGL(recur, dim3(NBLK), dim3(256), 0, stream, ra);

  // output projection + bias (f32 out)
  hipLaunchKernelGGL(gemm_bf16<1>, dim3(4, 128), dim3(256), 0, stream,
                     hs, ywp, (__hip_bfloat16*)nullptr, out, Yb, H_);
}

// Round 5
// 27754.373 us; speedup vs baseline: 2.5148x; 2.5148x over previous
//
#include <hip/hip_runtime.h>
#include <hip/hip_bf16.h>

typedef __bf16 bf16x8 __attribute__((ext_vector_type(8)));
typedef float  f32x4  __attribute__((ext_vector_type(4)));

#define B_ 32
#define S_ 512
#define I_ 256
#define H_ 1024
#define O_ 256
#define M_ (B_*S_)   // 16384
#define OUT_ELEMS ((size_t)B_*S_*O_)   // 4194304
#define NBLK 64

#define MFMA16(A,Bf,C) __builtin_amdgcn_mfma_f32_16x16x32_bf16(A,Bf,C,0,0,0)

// ---------------- elementwise converts ----------------
__global__ void cvt_f32_bf16(const float* __restrict__ src, __hip_bfloat16* __restrict__ dst, int n) {
  for (int i = blockIdx.x*blockDim.x + threadIdx.x; i < n; i += gridDim.x*blockDim.x)
    dst[i] = __float2bfloat16(src[i]);
}

// x [B][S][I] f32 -> xb [S][B][I] bf16
__global__ void xpose_x(const float* __restrict__ x, __hip_bfloat16* __restrict__ xb) {
  const int total = B_*S_*I_;
  for (int d = blockIdx.x*blockDim.x + threadIdx.x; d < total; d += gridDim.x*blockDim.x) {
    int i = d & (I_-1);
    int b = (d >> 8) & (B_-1);
    int s = d >> 13;
    xb[d] = __float2bfloat16(x[((size_t)b*S_ + s)*I_ + i]);
  }
}

// ---------------- GEMM: C[M][N] = A[M][K] * W[N][K]^T ----------------
// MODE 0: store bf16 to dstb[gate][m][h] (gate = n>>10).
// MODE 1: store f32 out[(b*S+s)*O + n] = v + bias[n], m = s*32+b.
template<int MODE>
__global__ __launch_bounds__(256) void gemm_bf16(
    const __hip_bfloat16* __restrict__ A,
    const __hip_bfloat16* __restrict__ W,
    __hip_bfloat16* __restrict__ dstb,
    float* __restrict__ dstf,
    const float* __restrict__ bias,
    int K)
{
  __shared__ __hip_bfloat16 As[128][32];
  __shared__ __hip_bfloat16 Ws[64][32];
  const int tid  = threadIdx.x;
  const int wid  = tid >> 6, lane = tid & 63;
  const int m0   = blockIdx.y * 128, n0 = blockIdx.x * 64;
  const int col  = lane & 15, kl = (lane >> 4) * 8;
  const int lrow = tid >> 2, lcol = (tid & 3) * 8;
  f32x4 acc[2][4] = {};

  for (int k0 = 0; k0 < K; k0 += 32) {
    __syncthreads();
    *(bf16x8*)&As[lrow][lcol]    = *(const bf16x8*)&A[(size_t)(m0+lrow)*K    + k0 + lcol];
    *(bf16x8*)&As[lrow+64][lcol] = *(const bf16x8*)&A[(size_t)(m0+lrow+64)*K + k0 + lcol];
    *(bf16x8*)&Ws[lrow][lcol]    = *(const bf16x8*)&W[(size_t)(n0+lrow)*K    + k0 + lcol];
    __syncthreads();
    bf16x8 a0 = *(const bf16x8*)&As[wid*32 + col][kl];
    bf16x8 a1 = *(const bf16x8*)&As[wid*32 + 16 + col][kl];
#pragma unroll
    for (int nt = 0; nt < 4; ++nt) {
      bf16x8 bw = *(const bf16x8*)&Ws[nt*16 + col][kl];
      acc[0][nt] = MFMA16(a0, bw, acc[0][nt]);
      acc[1][nt] = MFMA16(a1, bw, acc[1][nt]);
    }
  }
#pragma unroll
  for (int mt = 0; mt < 2; ++mt)
#pragma unroll
    for (int nt = 0; nt < 4; ++nt)
#pragma unroll
      for (int j = 0; j < 4; ++j) {
        int m = m0 + wid*32 + mt*16 + (lane>>4)*4 + j;
        int n = n0 + nt*16 + col;
        float v = acc[mt][nt][j];
        if (MODE == 0) {
          int gate = n >> 10, h = n & 1023;
          dstb[(size_t)gate*((size_t)M_*H_) + (size_t)m*H_ + h] = __float2bfloat16(v);
        } else {
          int s = m >> 5, b = m & 31;
          dstf[((size_t)b*S_ + s)*O_ + n] = v + bias[n];
        }
      }
}

// ---------------- grid barrier: relaxed spin + explicit fences ----------------
// Monotonic generation counter (zeroed by captured memsetAsync each launch).
// CRITICAL: the spin poll is RELAXED (an acquire atomic load on gfx9xx emits
// buffer_inv each poll -> L2-invalidate storm, the round-3 pathology).
__device__ __forceinline__ void gridbar(unsigned int* cnt, unsigned int target) {
  __syncthreads();
  __threadfence();   // release: publish this block's global writes
  if (threadIdx.x == 0) {
    __hip_atomic_fetch_add(cnt, 1u, __ATOMIC_RELAXED, __HIP_MEMORY_SCOPE_AGENT);
    while (__hip_atomic_load(cnt, __ATOMIC_RELAXED, __HIP_MEMORY_SCOPE_AGENT) < target)
      __builtin_amdgcn_s_sleep(2);
  }
  __syncthreads();
  __threadfence();   // acquire: invalidate stale cached lines
}

// ---------------- persistent recurrence, register-resident weights ----------------
// 64 blocks x 256 threads. Block blk owns output slice hh = blk*16 .. blk*16+15
// for ALL gates (z,r,g) and all 32 batches. Weights for the slice live in VGPRs
// (wz/wr/wg, 96 regs). h (f32) + z live in the epilogue threads' registers.
// Cross-block data per step: hb (bf16 h broadcast) and hrb (bf16 h*r broadcast).
struct RecurArgs {
  const __hip_bfloat16 *xz, *xr, *xg;  // [S][B][H] bf16
  const __hip_bfloat16 *W2;            // [3*H][H] bf16 (z, r, g row blocks)
  const float *bz, *br, *bg;           // [H]
  const float *h0;                     // initial h, stride 2*H per b
  __hip_bfloat16 *hb;                  // [B][H] bf16 h mirror
  __hip_bfloat16 *hrb;                 // [B][H] bf16 h*r
  __hip_bfloat16 *hs;                  // [S][B][H] bf16 outputs
  float *fin;                          // d_out hidden slot, stride 2*H per b
  unsigned int *bar;
};

__global__ __launch_bounds__(256, 1) void recur(RecurArgs a) {
  __shared__ f32x4 part[4][4][64];     // [wave][set][lane]
  const int tid = threadIdx.x, wid = tid >> 6, lane = tid & 63;
  const int col = lane & 15, kl = (lane >> 4) * 8;
  const int blk = blockIdx.x;          // 0..63
  const int hh  = blk*16 + col;        // this lane's output index (MFMA B-row)
  unsigned int tgt = 0;

  // ---- preload this slice's weights into registers (constant over t) ----
  bf16x8 wz[8], wr[8], wg[8];
  {
    const __hip_bfloat16* wp = a.W2 + (size_t)hh*H_ + wid*256 + kl;
#pragma unroll
    for (int kc = 0; kc < 8; ++kc) {
      wz[kc] = *(const bf16x8*)(wp + kc*32);
      wr[kc] = *(const bf16x8*)(wp + (size_t)1024*H_ + kc*32);
      wg[kc] = *(const bf16x8*)(wp + (size_t)2048*H_ + kc*32);
    }
  }

  // ---- persistent per-thread state (epilogue threads wid<2, mt=wid) ----
  float hreg[4] = {0,0,0,0}, zreg[4] = {0,0,0,0};
  float bzv = 0.f, brv = 0.f, bgv = 0.f;
  if (wid < 2) {
    bzv = a.bz[hh]; brv = a.br[hh]; bgv = a.bg[hh];
#pragma unroll
    for (int j = 0; j < 4; ++j) {
      int b = wid*16 + (lane>>4)*4 + j;
      hreg[j] = a.h0[(size_t)b*2048 + hh];
    }
  }
  // init global bf16 h mirror for this block's slice (all 32 batches)
  for (int k = tid; k < 512; k += 256) {
    int b = k >> 4, c = k & 15;
    a.hb[(size_t)b*H_ + blk*16 + c] = __float2bfloat16(a.h0[(size_t)b*2048 + blk*16 + c]);
  }
  tgt += NBLK; gridbar(a.bar, tgt);

  for (int t = 0; t < S_; ++t) {
    // x-addend prefetch (independent of recurrence; overlaps phase-A loads)
    float xzv[4], xrv[4], xgv[4];
    if (wid < 2) {
#pragma unroll
      for (int j = 0; j < 4; ++j) {
        int b = wid*16 + (lane>>4)*4 + j;
        size_t o = (size_t)t*(B_*H_) + (size_t)b*H_ + hh;
        xzv[j] = __bfloat162float(a.xz[o]);
        xrv[j] = __bfloat162float(a.xr[o]);
        xgv[j] = __bfloat162float(a.xg[o]);
      }
    }

    // ---- phase A: z and r pre-activations (K split across 4 waves) ----
    {
      f32x4 az0 = {0,0,0,0}, az1 = {0,0,0,0}, ar0 = {0,0,0,0}, ar1 = {0,0,0,0};
      const __hip_bfloat16* hp0 = a.hb + (size_t)col*H_ + wid*256 + kl;
      const __hip_bfloat16* hp1 = hp0 + (size_t)16*H_;
#pragma unroll
      for (int kc = 0; kc < 8; ++kc) {
        bf16x8 h0f = *(const bf16x8*)(hp0 + kc*32);
        bf16x8 h1f = *(const bf16x8*)(hp1 + kc*32);
        az0 = MFMA16(h0f, wz[kc], az0);
        az1 = MFMA16(h1f, wz[kc], az1);
        ar0 = MFMA16(h0f, wr[kc], ar0);
        ar1 = MFMA16(h1f, wr[kc], ar1);
      }
      part[wid][0][lane] = az0; part[wid][1][lane] = az1;
      part[wid][2][lane] = ar0; part[wid][3][lane] = ar1;
    }
    __syncthreads();
    if (wid < 2) {
      f32x4 zs = part[0][wid][lane] + part[1][wid][lane] + part[2][wid][lane] + part[3][wid][lane];
      f32x4 rs = part[0][2+wid][lane] + part[1][2+wid][lane] + part[2][2+wid][lane] + part[3][2+wid][lane];
#pragma unroll
      for (int j = 0; j < 4; ++j) {
        int b = wid*16 + (lane>>4)*4 + j;
        float z = 1.f / (1.f + __expf(-(zs[j] + xzv[j] + bzv)));
        float r = 1.f / (1.f + __expf(-(rs[j] + xrv[j] + brv)));
        zreg[j] = z;
        a.hrb[(size_t)b*H_ + hh] = __float2bfloat16(r * hreg[j]);  // f32 h * f32 r
      }
    }
    tgt += NBLK; gridbar(a.bar, tgt);

    // ---- phase B: g pre-activation + state update ----
    {
      f32x4 ag0 = {0,0,0,0}, ag1 = {0,0,0,0};
      const __hip_bfloat16* hp0 = a.hrb + (size_t)col*H_ + wid*256 + kl;
      const __hip_bfloat16* hp1 = hp0 + (size_t)16*H_;
#pragma unroll
      for (int kc = 0; kc < 8; ++kc) {
        bf16x8 h0f = *(const bf16x8*)(hp0 + kc*32);
        bf16x8 h1f = *(const bf16x8*)(hp1 + kc*32);
        ag0 = MFMA16(h0f, wg[kc], ag0);
        ag1 = MFMA16(h1f, wg[kc], ag1);
      }
      part[wid][0][lane] = ag0; part[wid][1][lane] = ag1;
    }
    __syncthreads();
    if (wid < 2) {
      f32x4 gs = part[0][wid][lane] + part[1][wid][lane] + part[2][wid][lane] + part[3][wid][lane];
#pragma unroll
      for (int j = 0; j < 4; ++j) {
        int b = wid*16 + (lane>>4)*4 + j;
        float g  = tanhf(gs[j] + xgv[j] + bgv);
        float hn = zreg[j]*hreg[j] + (1.f - zreg[j])*g;
        hreg[j] = hn;
        __hip_bfloat16 hnb = __float2bfloat16(hn);
        a.hb[(size_t)b*H_ + hh] = hnb;
        a.hs[((size_t)t*B_ + b)*H_ + hh] = hnb;
        if (t == S_-2) a.fin[(size_t)b*2048 + hh] = hn;
      }
    }
    tgt += NBLK; gridbar(a.bar, tgt);
  }
}

// ---------------- host ----------------
extern "C" void kernel_launch(void* const* d_in, const int* in_sizes, int n_in,
                              void* d_out, int out_size, void* d_ws, size_t ws_size,
                              hipStream_t stream) {
  (void)in_sizes; (void)n_in; (void)out_size; (void)ws_size;
  const float* x     = (const float*)d_in[0];
  const float* hid0  = (const float*)d_in[1];
  const float* z1_0  = (const float*)d_in[2];
  const float* z2_0  = (const float*)d_in[3];
  const float* z2b_0 = (const float*)d_in[4];
  const float* r1_0  = (const float*)d_in[5];
  const float* r2_0  = (const float*)d_in[6];
  const float* r2b_0 = (const float*)d_in[7];
  const float* g1_0  = (const float*)d_in[8];
  const float* g2_0  = (const float*)d_in[9];
  const float* g2b_0 = (const float*)d_in[10];
  const float* z1_1  = (const float*)d_in[11];
  const float* z2_1  = (const float*)d_in[12];
  const float* z2b_1 = (const float*)d_in[13];
  const float* r1_1  = (const float*)d_in[14];
  const float* r2_1  = (const float*)d_in[15];
  const float* r2b_1 = (const float*)d_in[16];
  const float* g1_1  = (const float*)d_in[17];
  const float* g2_1  = (const float*)d_in[18];
  const float* g2b_1 = (const float*)d_in[19];
  const float* Yw    = (const float*)d_in[20];
  const float* Yb    = (const float*)d_in[21];
  float* out = (float*)d_out;

  char* ws = (char*)d_ws;
  size_t off = 0;
  auto alloc = [&](size_t bytes) -> void* {
    void* p = ws + off; off += (bytes + 255) & ~(size_t)255; return p;
  };
  __hip_bfloat16* xproj = (__hip_bfloat16*)alloc((size_t)3*M_*H_*2);  // 96 MB
  __hip_bfloat16* hs    = (__hip_bfloat16*)alloc((size_t)M_*H_*2);    // 32 MB
  __hip_bfloat16* xb    = (__hip_bfloat16*)alloc((size_t)M_*I_*2);
  __hip_bfloat16* w1p0  = (__hip_bfloat16*)alloc((size_t)3*H_*I_*2);
  __hip_bfloat16* w1p1  = (__hip_bfloat16*)alloc((size_t)3*H_*H_*2);
  __hip_bfloat16* w2p0  = (__hip_bfloat16*)alloc((size_t)3*H_*H_*2);
  __hip_bfloat16* w2p1  = (__hip_bfloat16*)alloc((size_t)3*H_*H_*2);
  __hip_bfloat16* ywp   = (__hip_bfloat16*)alloc((size_t)O_*H_*2);
  __hip_bfloat16* hbc   = (__hip_bfloat16*)alloc((size_t)B_*H_*2);
  __hip_bfloat16* hrb   = (__hip_bfloat16*)alloc((size_t)B_*H_*2);
  unsigned int*   bars  = (unsigned int*)  alloc(512);

  hipMemsetAsync(bars, 0, 512, stream);

  hipLaunchKernelGGL(xpose_x, dim3(2048), dim3(256), 0, stream, x, xb);
  auto CVT = [&](const float* s, __hip_bfloat16* d, int n) {
    hipLaunchKernelGGL(cvt_f32_bf16, dim3(512), dim3(256), 0, stream, s, d, n);
  };
  CVT(z1_0, w1p0,            H_*I_);
  CVT(r1_0, w1p0 + H_*I_,    H_*I_);
  CVT(g1_0, w1p0 + 2*H_*I_,  H_*I_);
  CVT(z2_0, w2p0,            H_*H_);
  CVT(r2_0, w2p0 + H_*H_,    H_*H_);
  CVT(g2_0, w2p0 + 2*H_*H_,  H_*H_);
  CVT(z1_1, w1p1,            H_*H_);
  CVT(r1_1, w1p1 + H_*H_,    H_*H_);
  CVT(g1_1, w1p1 + 2*H_*H_,  H_*H_);
  CVT(z2_1, w2p1,            H_*H_);
  CVT(r2_1, w2p1 + H_*H_,    H_*H_);
  CVT(g2_1, w2p1 + 2*H_*H_,  H_*H_);
  CVT(Yw,   ywp,             O_*H_);

  // layer 0 input projections (K=256)
  hipLaunchKernelGGL(gemm_bf16<0>, dim3(48, 128), dim3(256), 0, stream,
                     xb, w1p0, xproj, (float*)nullptr, (const float*)nullptr, I_);

  // layer 0 recurrence
  RecurArgs ra;
  ra.xz = xproj;
  ra.xr = xproj + (size_t)M_*H_;
  ra.xg = xproj + (size_t)2*M_*H_;
  ra.W2 = w2p0; ra.bz = z2b_0; ra.br = r2b_0; ra.bg = g2b_0;
  ra.h0 = hid0;
  ra.hb = hbc; ra.hrb = hrb;
  ra.hs = hs;
  ra.fin = out + OUT_ELEMS;
  ra.bar = bars;
  hipLaunchKernelGGL(recur, dim3(NBLK), dim3(256), 0, stream, ra);

  // layer 1 input projections (K=1024)
  hipLaunchKernelGGL(gemm_bf16<0>, dim3(48, 128), dim3(256), 0, stream,
                     hs, w1p1, xproj, (float*)nullptr, (const float*)nullptr, H_);

  // layer 1 recurrence
  ra.W2 = w2p1; ra.bz = z2b_1; ra.br = r2b_1; ra.bg = g2b_1;
  ra.h0 = hid0 + 1024;
  ra.hs = hs;
  ra.fin = out + OUT_ELEMS + 1024;
  ra.bar = bars + 64;
  hipLaunchKernelGGL(recur, dim3(NBLK), dim3(256), 0, stream, ra);

  // output projection + bias
  hipLaunchKernelGGL(gemm_bf16<1>, dim3(4, 128), dim3(256), 0, stream,
                     hs, ywp, (__hip_bfloat16*)nullptr, out, Yb, H_);
}

// Round 6
// 12642.898 us; speedup vs baseline: 5.5205x; 2.1953x over previous
//
#include <hip/hip_runtime.h>
#include <hip/hip_bf16.h>

typedef __bf16 bf16x8 __attribute__((ext_vector_type(8)));
typedef float  f32x4  __attribute__((ext_vector_type(4)));
typedef unsigned long long u64;

#define B_ 32
#define S_ 512
#define I_ 256
#define H_ 1024
#define O_ 256
#define M_ (B_*S_)   // 16384
#define OUT_ELEMS ((size_t)B_*S_*O_)   // 4194304
#define NBLK 64

#define MFMA16(A,Bf,C) __builtin_amdgcn_mfma_f32_16x16x32_bf16(A,Bf,C,0,0,0)

union U16x8 { u64 q[2]; bf16x8 v; };

// agent-scope relaxed atomics: bypass L1/L2 to the coherence point (MALL).
// ALL hb/hrb accesses go through these -> no threadfence/L2-invalidate needed.
__device__ __forceinline__ u64 aload(const __hip_bfloat16* p) {
  return __hip_atomic_load((const u64*)p, __ATOMIC_RELAXED, __HIP_MEMORY_SCOPE_AGENT);
}
__device__ __forceinline__ void astore(__hip_bfloat16* p, u64 v) {
  __hip_atomic_store((u64*)p, v, __ATOMIC_RELAXED, __HIP_MEMORY_SCOPE_AGENT);
}
__device__ __forceinline__ unsigned short f2bf(float f) {
  __hip_bfloat16 h = __float2bfloat16(f);
  unsigned short s; __builtin_memcpy(&s, &h, 2); return s;
}
__device__ __forceinline__ float bf2f(unsigned short s) {
  unsigned int u = (unsigned int)s << 16; float f; __builtin_memcpy(&f, &u, 4); return f;
}

// ---------------- elementwise converts ----------------
__global__ void cvt_f32_bf16(const float* __restrict__ src, __hip_bfloat16* __restrict__ dst, int n) {
  for (int i = blockIdx.x*blockDim.x + threadIdx.x; i < n; i += gridDim.x*blockDim.x)
    dst[i] = __float2bfloat16(src[i]);
}

// x [B][S][I] f32 -> xb [S][B][I] bf16
__global__ void xpose_x(const float* __restrict__ x, __hip_bfloat16* __restrict__ xb) {
  const int total = B_*S_*I_;
  for (int d = blockIdx.x*blockDim.x + threadIdx.x; d < total; d += gridDim.x*blockDim.x) {
    int i = d & (I_-1);
    int b = (d >> 8) & (B_-1);
    int s = d >> 13;
    xb[d] = __float2bfloat16(x[((size_t)b*S_ + s)*I_ + i]);
  }
}

// ---------------- GEMM: C[M][N] = A[M][K] * W[N][K]^T ----------------
template<int MODE>
__global__ __launch_bounds__(256) void gemm_bf16(
    const __hip_bfloat16* __restrict__ A,
    const __hip_bfloat16* __restrict__ W,
    __hip_bfloat16* __restrict__ dstb,
    float* __restrict__ dstf,
    const float* __restrict__ bias,
    int K)
{
  __shared__ __hip_bfloat16 As[128][32];
  __shared__ __hip_bfloat16 Ws[64][32];
  const int tid  = threadIdx.x;
  const int wid  = tid >> 6, lane = tid & 63;
  const int m0   = blockIdx.y * 128, n0 = blockIdx.x * 64;
  const int col  = lane & 15, kl = (lane >> 4) * 8;
  const int lrow = tid >> 2, lcol = (tid & 3) * 8;
  f32x4 acc[2][4] = {};

  for (int k0 = 0; k0 < K; k0 += 32) {
    __syncthreads();
    *(bf16x8*)&As[lrow][lcol]    = *(const bf16x8*)&A[(size_t)(m0+lrow)*K    + k0 + lcol];
    *(bf16x8*)&As[lrow+64][lcol] = *(const bf16x8*)&A[(size_t)(m0+lrow+64)*K + k0 + lcol];
    *(bf16x8*)&Ws[lrow][lcol]    = *(const bf16x8*)&W[(size_t)(n0+lrow)*K    + k0 + lcol];
    __syncthreads();
    bf16x8 a0 = *(const bf16x8*)&As[wid*32 + col][kl];
    bf16x8 a1 = *(const bf16x8*)&As[wid*32 + 16 + col][kl];
#pragma unroll
    for (int nt = 0; nt < 4; ++nt) {
      bf16x8 bw = *(const bf16x8*)&Ws[nt*16 + col][kl];
      acc[0][nt] = MFMA16(a0, bw, acc[0][nt]);
      acc[1][nt] = MFMA16(a1, bw, acc[1][nt]);
    }
  }
#pragma unroll
  for (int mt = 0; mt < 2; ++mt)
#pragma unroll
    for (int nt = 0; nt < 4; ++nt)
#pragma unroll
      for (int j = 0; j < 4; ++j) {
        int m = m0 + wid*32 + mt*16 + (lane>>4)*4 + j;
        int n = n0 + nt*16 + col;
        float v = acc[mt][nt][j];
        if (MODE == 0) {
          int gate = n >> 10, h = n & 1023;
          dstb[(size_t)gate*((size_t)M_*H_) + (size_t)m*H_ + h] = __float2bfloat16(v);
        } else {
          int s = m >> 5, b = m & 31;
          dstf[((size_t)b*S_ + s)*O_ + n] = v + bias[n];
        }
      }
}

// ---------------- flag barrier (arrival/poll decoupled) ----------------
// bars layout (uints): sub-counters at [i*64], i=0..7 (256B apart); go at [512].
// Arrivals: one relaxed agent fetch_add per block, spread over 8 lines.
// Leader (blk 0) alone polls the counters, then publishes epoch to `go`.
// Followers poll the read-only `go` line. All counters monotonic; zeroed by a
// captured hipMemsetAsync each launch.
__device__ __forceinline__ void gridbar(unsigned int* bars, unsigned int epoch, int blk) {
  __syncthreads();   // compiler emits vmcnt(0) drain before s_barrier -> stores visible
  if (threadIdx.x == 0) {
    __hip_atomic_fetch_add(&bars[(blk & 7) * 64], 1u, __ATOMIC_RELAXED, __HIP_MEMORY_SCOPE_AGENT);
    if (blk == 0) {
      for (;;) {
        unsigned int s = 0;
#pragma unroll
        for (int i = 0; i < 8; ++i)
          s += __hip_atomic_load(&bars[i * 64], __ATOMIC_RELAXED, __HIP_MEMORY_SCOPE_AGENT);
        if (s >= epoch * NBLK) break;
      }
      __hip_atomic_store(&bars[512], epoch, __ATOMIC_RELAXED, __HIP_MEMORY_SCOPE_AGENT);
    } else {
      while (__hip_atomic_load(&bars[512], __ATOMIC_RELAXED, __HIP_MEMORY_SCOPE_AGENT) < epoch)
        __builtin_amdgcn_s_sleep(1);
    }
  }
  __syncthreads();
}

// ---------------- persistent recurrence ----------------
// 64 blocks x 256 threads; block owns hh-slice blk*16..+15 for all gates/batches.
// Weights in VGPRs. D = W x h (swapped): row=hh-local, col=batch -> epilogue
// thread owns 4 consecutive hh for one batch -> 8B/16B vector accesses.
struct RecurArgs {
  const __hip_bfloat16 *xz, *xr, *xg;  // [S][B][H] bf16
  const __hip_bfloat16 *W2;            // [3*H][H] bf16 (z, r, g row blocks)
  const float *bz, *br, *bg;           // [H]
  const float *h0;                     // initial h, stride 2*H per b
  __hip_bfloat16 *hb;                  // [B][H] bf16 h mirror      (atomic-only)
  __hip_bfloat16 *hrb;                 // [B][H] bf16 h*r           (atomic-only)
  __hip_bfloat16 *hs;                  // [S][B][H] bf16 outputs
  float *fin;                          // d_out hidden slot, stride 2*H per b
  unsigned int *bar;
};

__global__ __launch_bounds__(256, 1) void recur(RecurArgs a) {
  __shared__ f32x4 part[4][4][64];     // [wave][set][lane]
  const int tid = threadIdx.x, wid = tid >> 6, lane = tid & 63;
  const int col = lane & 15, kl = (lane >> 4) * 8;
  const int blk = blockIdx.x;          // 0..63
  unsigned int epoch = 0;

  // ---- preload slice weights into registers (A-operand: row=hh-local=col) ----
  bf16x8 wz[8], wr[8], wg[8];
  {
    const __hip_bfloat16* wp = a.W2 + (size_t)(blk*16 + col)*H_ + wid*256 + kl;
#pragma unroll
    for (int kc = 0; kc < 8; ++kc) {
      wz[kc] = *(const bf16x8*)(wp + kc*32);
      wr[kc] = *(const bf16x8*)(wp + (size_t)1024*H_ + kc*32);
      wg[kc] = *(const bf16x8*)(wp + (size_t)2048*H_ + kc*32);
    }
  }

  // ---- persistent per-thread state (epilogue threads: wid<2) ----
  // b = wid*16 + (lane&15); hh0 = blk*16 + (lane>>4)*4  (4 consecutive hh)
  const int b   = wid*16 + (lane & 15);
  const int hh0 = blk*16 + (lane >> 4)*4;
  float hreg[4] = {0,0,0,0}, zreg[4] = {0,0,0,0};
  f32x4 bz4 = {0,0,0,0}, br4 = {0,0,0,0}, bg4 = {0,0,0,0};
  if (wid < 2) {
    bz4 = *(const f32x4*)(a.bz + hh0);
    br4 = *(const f32x4*)(a.br + hh0);
    bg4 = *(const f32x4*)(a.bg + hh0);
    f32x4 h4 = *(const f32x4*)(a.h0 + (size_t)b*2048 + hh0);
#pragma unroll
    for (int j = 0; j < 4; ++j) hreg[j] = h4[j];
  }
  // init global bf16 h mirror for this block's slice (atomic stores only)
  if (tid < 128) {
    int bb = tid >> 2, hi = blk*16 + (tid & 3)*4;
    f32x4 v = *(const f32x4*)(a.h0 + (size_t)bb*2048 + hi);
    u64 pk = 0;
#pragma unroll
    for (int j = 0; j < 4; ++j) pk |= (u64)f2bf(v[j]) << (16*j);
    astore(&a.hb[(size_t)bb*H_ + hi], pk);
  }
  gridbar(a.bar, ++epoch, blk);

  for (int t = 0; t < S_; ++t) {
    // x addends (regular cacheable loads; L2 locality preserved — no fences)
    float xzv[4], xrv[4], xgv[4];
    if (wid < 2) {
      size_t o = (size_t)t*(B_*H_) + (size_t)b*H_ + hh0;
      u64 qz = *(const u64*)(const void*)(a.xz + o);
      u64 qr = *(const u64*)(const void*)(a.xr + o);
      u64 qg = *(const u64*)(const void*)(a.xg + o);
#pragma unroll
      for (int j = 0; j < 4; ++j) {
        xzv[j] = bf2f((unsigned short)(qz >> (16*j)));
        xrv[j] = bf2f((unsigned short)(qr >> (16*j)));
        xgv[j] = bf2f((unsigned short)(qg >> (16*j)));
      }
    }

    // ---- phase A: z and r pre-activations (K split across 4 waves) ----
    {
      f32x4 az0 = {0,0,0,0}, az1 = {0,0,0,0}, ar0 = {0,0,0,0}, ar1 = {0,0,0,0};
      const __hip_bfloat16* hp0 = a.hb + (size_t)col*H_ + wid*256 + kl;
      const __hip_bfloat16* hp1 = hp0 + (size_t)16*H_;
#pragma unroll
      for (int kc = 0; kc < 8; ++kc) {
        U16x8 u0, u1;
        u0.q[0] = aload(hp0 + kc*32); u0.q[1] = aload(hp0 + kc*32 + 4);
        u1.q[0] = aload(hp1 + kc*32); u1.q[1] = aload(hp1 + kc*32 + 4);
        az0 = MFMA16(wz[kc], u0.v, az0);
        az1 = MFMA16(wz[kc], u1.v, az1);
        ar0 = MFMA16(wr[kc], u0.v, ar0);
        ar1 = MFMA16(wr[kc], u1.v, ar1);
      }
      part[wid][0][lane] = az0; part[wid][1][lane] = az1;
      part[wid][2][lane] = ar0; part[wid][3][lane] = ar1;
    }
    __syncthreads();
    if (wid < 2) {
      f32x4 zs = part[0][wid][lane] + part[1][wid][lane] + part[2][wid][lane] + part[3][wid][lane];
      f32x4 rs = part[0][2+wid][lane] + part[1][2+wid][lane] + part[2][2+wid][lane] + part[3][2+wid][lane];
      u64 pk = 0;
#pragma unroll
      for (int j = 0; j < 4; ++j) {
        float z = 1.f / (1.f + __expf(-(zs[j] + xzv[j] + bz4[j])));
        float r = 1.f / (1.f + __expf(-(rs[j] + xrv[j] + br4[j])));
        zreg[j] = z;
        pk |= (u64)f2bf(r * hreg[j]) << (16*j);
      }
      astore(&a.hrb[(size_t)b*H_ + hh0], pk);
    }
    gridbar(a.bar, ++epoch, blk);

    // ---- phase B: g pre-activation + state update ----
    {
      f32x4 ag0 = {0,0,0,0}, ag1 = {0,0,0,0};
      const __hip_bfloat16* hp0 = a.hrb + (size_t)col*H_ + wid*256 + kl;
      const __hip_bfloat16* hp1 = hp0 + (size_t)16*H_;
#pragma unroll
      for (int kc = 0; kc < 8; ++kc) {
        U16x8 u0, u1;
        u0.q[0] = aload(hp0 + kc*32); u0.q[1] = aload(hp0 + kc*32 + 4);
        u1.q[0] = aload(hp1 + kc*32); u1.q[1] = aload(hp1 + kc*32 + 4);
        ag0 = MFMA16(wg[kc], u0.v, ag0);
        ag1 = MFMA16(wg[kc], u1.v, ag1);
      }
      part[wid][0][lane] = ag0; part[wid][1][lane] = ag1;
    }
    __syncthreads();
    if (wid < 2) {
      f32x4 gs = part[0][wid][lane] + part[1][wid][lane] + part[2][wid][lane] + part[3][wid][lane];
      u64 pk = 0; f32x4 fv;
#pragma unroll
      for (int j = 0; j < 4; ++j) {
        float g  = tanhf(gs[j] + xgv[j] + bg4[j]);
        float hn = zreg[j]*hreg[j] + (1.f - zreg[j])*g;
        hreg[j] = hn; fv[j] = hn;
        pk |= (u64)f2bf(hn) << (16*j);
      }
      astore(&a.hb[(size_t)b*H_ + hh0], pk);
      *(u64*)(void*)(a.hs + ((size_t)t*B_ + b)*H_ + hh0) = pk;
      if (t == S_-2) *(f32x4*)(a.fin + (size_t)b*2048 + hh0) = fv;
    }
    gridbar(a.bar, ++epoch, blk);
  }
}

// ---------------- host ----------------
extern "C" void kernel_launch(void* const* d_in, const int* in_sizes, int n_in,
                              void* d_out, int out_size, void* d_ws, size_t ws_size,
                              hipStream_t stream) {
  (void)in_sizes; (void)n_in; (void)out_size; (void)ws_size;
  const float* x     = (const float*)d_in[0];
  const float* hid0  = (const float*)d_in[1];
  const float* z1_0  = (const float*)d_in[2];
  const float* z2_0  = (const float*)d_in[3];
  const float* z2b_0 = (const float*)d_in[4];
  const float* r1_0  = (const float*)d_in[5];
  const float* r2_0  = (const float*)d_in[6];
  const float* r2b_0 = (const float*)d_in[7];
  const float* g1_0  = (const float*)d_in[8];
  const float* g2_0  = (const float*)d_in[9];
  const float* g2b_0 = (const float*)d_in[10];
  const float* z1_1  = (const float*)d_in[11];
  const float* z2_1  = (const float*)d_in[12];
  const float* z2b_1 = (const float*)d_in[13];
  const float* r1_1  = (const float*)d_in[14];
  const float* r2_1  = (const float*)d_in[15];
  const float* r2b_1 = (const float*)d_in[16];
  const float* g1_1  = (const float*)d_in[17];
  const float* g2_1  = (const float*)d_in[18];
  const float* g2b_1 = (const float*)d_in[19];
  const float* Yw    = (const float*)d_in[20];
  const float* Yb    = (const float*)d_in[21];
  float* out = (float*)d_out;

  char* ws = (char*)d_ws;
  size_t off = 0;
  auto alloc = [&](size_t bytes) -> void* {
    void* p = ws + off; off += (bytes + 255) & ~(size_t)255; return p;
  };
  __hip_bfloat16* xproj = (__hip_bfloat16*)alloc((size_t)3*M_*H_*2);  // 96 MB
  __hip_bfloat16* hs    = (__hip_bfloat16*)alloc((size_t)M_*H_*2);    // 32 MB
  __hip_bfloat16* xb    = (__hip_bfloat16*)alloc((size_t)M_*I_*2);
  __hip_bfloat16* w1p0  = (__hip_bfloat16*)alloc((size_t)3*H_*I_*2);
  __hip_bfloat16* w1p1  = (__hip_bfloat16*)alloc((size_t)3*H_*H_*2);
  __hip_bfloat16* w2p0  = (__hip_bfloat16*)alloc((size_t)3*H_*H_*2);
  __hip_bfloat16* w2p1  = (__hip_bfloat16*)alloc((size_t)3*H_*H_*2);
  __hip_bfloat16* ywp   = (__hip_bfloat16*)alloc((size_t)O_*H_*2);
  __hip_bfloat16* hbc   = (__hip_bfloat16*)alloc((size_t)B_*H_*2);
  __hip_bfloat16* hrb   = (__hip_bfloat16*)alloc((size_t)B_*H_*2);
  unsigned int*   bars  = (unsigned int*)  alloc(8192);   // 2 layers x 1024 uints

  hipMemsetAsync(bars, 0, 8192, stream);

  hipLaunchKernelGGL(xpose_x, dim3(2048), dim3(256), 0, stream, x, xb);
  auto CVT = [&](const float* s, __hip_bfloat16* d, int n) {
    hipLaunchKernelGGL(cvt_f32_bf16, dim3(512), dim3(256), 0, stream, s, d, n);
  };
  CVT(z1_0, w1p0,            H_*I_);
  CVT(r1_0, w1p0 + H_*I_,    H_*I_);
  CVT(g1_0, w1p0 + 2*H_*I_,  H_*I_);
  CVT(z2_0, w2p0,            H_*H_);
  CVT(r2_0, w2p0 + H_*H_,    H_*H_);
  CVT(g2_0, w2p0 + 2*H_*H_,  H_*H_);
  CVT(z1_1, w1p1,            H_*H_);
  CVT(r1_1, w1p1 + H_*H_,    H_*H_);
  CVT(g1_1, w1p1 + 2*H_*H_,  H_*H_);
  CVT(z2_1, w2p1,            H_*H_);
  CVT(r2_1, w2p1 + H_*H_,    H_*H_);
  CVT(g2_1, w2p1 + 2*H_*H_,  H_*H_);
  CVT(Yw,   ywp,             O_*H_);

  // layer 0 input projections (K=256)
  hipLaunchKernelGGL(gemm_bf16<0>, dim3(48, 128), dim3(256), 0, stream,
                     xb, w1p0, xproj, (float*)nullptr, (const float*)nullptr, I_);

  // layer 0 recurrence
  RecurArgs ra;
  ra.xz = xproj;
  ra.xr = xproj + (size_t)M_*H_;
  ra.xg = xproj + (size_t)2*M_*H_;
  ra.W2 = w2p0; ra.bz = z2b_0; ra.br = r2b_0; ra.bg = g2b_0;
  ra.h0 = hid0;
  ra.hb = hbc; ra.hrb = hrb;
  ra.hs = hs;
  ra.fin = out + OUT_ELEMS;
  ra.bar = bars;
  hipLaunchKernelGGL(recur, dim3(NBLK), dim3(256), 0, stream, ra);

  // layer 1 input projections (K=1024)
  hipLaunchKernelGGL(gemm_bf16<0>, dim3(48, 128), dim3(256), 0, stream,
                     hs, w1p1, xproj, (float*)nullptr, (const float*)nullptr, H_);

  // layer 1 recurrence
  ra.W2 = w2p1; ra.bz = z2b_1; ra.br = r2b_1; ra.bg = g2b_1;
  ra.h0 = hid0 + 1024;
  ra.hs = hs;
  ra.fin = out + OUT_ELEMS + 1024;
  ra.bar = bars + 1024;
  hipLaunchKernelGGL(recur, dim3(NBLK), dim3(256), 0, stream, ra);

  // output projection + bias
  hipLaunchKernelGGL(gemm_bf16<1>, dim3(4, 128), dim3(256), 0, stream,
                     hs, ywp, (__hip_bfloat16*)nullptr, out, Yb, H_);
}

// Round 7
// 9982.565 us; speedup vs baseline: 6.9917x; 1.2665x over previous
//
#include <hip/hip_runtime.h>
#include <hip/hip_bf16.h>

typedef __bf16 bf16x8 __attribute__((ext_vector_type(8)));
typedef float  f32x4  __attribute__((ext_vector_type(4)));
typedef unsigned long long u64;

#define B_ 32
#define S_ 512
#define I_ 256
#define H_ 1024
#define O_ 256
#define M_ (B_*S_)   // 16384
#define OUT_ELEMS ((size_t)B_*S_*O_)   // 4194304

#define MFMA16(A,Bf,C) __builtin_amdgcn_mfma_f32_16x16x32_bf16(A,Bf,C,0,0,0)

union U16x8 { u64 q[2]; bf16x8 v; };

// agent-scope relaxed atomics: bypass L1/L2 to the coherence point (MALL).
__device__ __forceinline__ u64 aload(const __hip_bfloat16* p) {
  return __hip_atomic_load((const u64*)p, __ATOMIC_RELAXED, __HIP_MEMORY_SCOPE_AGENT);
}
__device__ __forceinline__ void astore(__hip_bfloat16* p, u64 v) {
  __hip_atomic_store((u64*)p, v, __ATOMIC_RELAXED, __HIP_MEMORY_SCOPE_AGENT);
}
__device__ __forceinline__ unsigned int aload32(const unsigned int* p) {
  return __hip_atomic_load(p, __ATOMIC_RELAXED, __HIP_MEMORY_SCOPE_AGENT);
}
__device__ __forceinline__ void astore32(unsigned int* p, unsigned int v) {
  __hip_atomic_store(p, v, __ATOMIC_RELAXED, __HIP_MEMORY_SCOPE_AGENT);
}
__device__ __forceinline__ unsigned short f2bf(float f) {
  __hip_bfloat16 h = __float2bfloat16(f);
  unsigned short s; __builtin_memcpy(&s, &h, 2); return s;
}

// ---------------- elementwise converts ----------------
__global__ void cvt_f32_bf16(const float* __restrict__ src, __hip_bfloat16* __restrict__ dst, int n) {
  for (int i = blockIdx.x*blockDim.x + threadIdx.x; i < n; i += gridDim.x*blockDim.x)
    dst[i] = __float2bfloat16(src[i]);
}

// x [B][S][I] f32 -> xb [S][B][I] bf16
__global__ void xpose_x(const float* __restrict__ x, __hip_bfloat16* __restrict__ xb) {
  const int total = B_*S_*I_;
  for (int d = blockIdx.x*blockDim.x + threadIdx.x; d < total; d += gridDim.x*blockDim.x) {
    int i = d & (I_-1);
    int b = (d >> 8) & (B_-1);
    int s = d >> 13;
    xb[d] = __float2bfloat16(x[((size_t)b*S_ + s)*I_ + i]);
  }
}

// ---------------- output GEMM: out[(b*S+s)*O+n] = hs2[m]*Yw^T + Yb ----------------
__global__ __launch_bounds__(256) void gemm_out(
    const __hip_bfloat16* __restrict__ A,   // [M][H] = hs2
    const __hip_bfloat16* __restrict__ W,   // [O][H]
    float* __restrict__ dstf,
    const float* __restrict__ bias)
{
  __shared__ __hip_bfloat16 As[128][32];
  __shared__ __hip_bfloat16 Ws[64][32];
  const int tid  = threadIdx.x;
  const int wid  = tid >> 6, lane = tid & 63;
  const int m0   = blockIdx.y * 128, n0 = blockIdx.x * 64;
  const int col  = lane & 15, kl = (lane >> 4) * 8;
  const int lrow = tid >> 2, lcol = (tid & 3) * 8;
  f32x4 acc[2][4] = {};

  for (int k0 = 0; k0 < H_; k0 += 32) {
    __syncthreads();
    *(bf16x8*)&As[lrow][lcol]    = *(const bf16x8*)&A[(size_t)(m0+lrow)*H_    + k0 + lcol];
    *(bf16x8*)&As[lrow+64][lcol] = *(const bf16x8*)&A[(size_t)(m0+lrow+64)*H_ + k0 + lcol];
    *(bf16x8*)&Ws[lrow][lcol]    = *(const bf16x8*)&W[(size_t)(n0+lrow)*H_    + k0 + lcol];
    __syncthreads();
    bf16x8 a0 = *(const bf16x8*)&As[wid*32 + col][kl];
    bf16x8 a1 = *(const bf16x8*)&As[wid*32 + 16 + col][kl];
#pragma unroll
    for (int nt = 0; nt < 4; ++nt) {
      bf16x8 bw = *(const bf16x8*)&Ws[nt*16 + col][kl];
      acc[0][nt] = MFMA16(a0, bw, acc[0][nt]);
      acc[1][nt] = MFMA16(a1, bw, acc[1][nt]);
    }
  }
#pragma unroll
  for (int mt = 0; mt < 2; ++mt)
#pragma unroll
    for (int nt = 0; nt < 4; ++nt)
#pragma unroll
      for (int j = 0; j < 4; ++j) {
        int m = m0 + wid*32 + mt*16 + (lane>>4)*4 + j;
        int n = n0 + nt*16 + col;
        int s = m >> 5, b = m & 31;
        dstf[((size_t)b*S_ + s)*O_ + n] = acc[mt][nt][j] + bias[n];
      }
}

// ---------------- fused 2-layer persistent recurrence ----------------
// 128 blocks x 256 thr: blocks 0..63 = layer 0, 64..127 = layer 1 (pipelined
// 1 step behind, consuming hs1[t] through MALL). Input projections fused as a
// second K-pass per phase (W1 slices in VGPRs) -> no xproj buffers/GEMMs.
// All-to-all flag barrier: block stores epoch to flag[sub]; wave0 lanes spin
// on one flag each (coalesced 256B poll). Epochs: init=1, step t: A=2t+2,
// B=2t+3. L1 step t additionally waits flag0[*] >= 2t+3 (hs1[t] ready).
struct R2Args {
  const __hip_bfloat16 *xb;                      // [S][B][I]
  const __hip_bfloat16 *w1_0, *w2_0, *w1_1, *w2_1;
  const float *bz0,*br0,*bg0,*bz1,*br1,*bg1;
  const float *h0;                               // [B][2][H]
  __hip_bfloat16 *hb0,*hrb0,*hb1,*hrb1;          // [B][H] (MALL-only)
  __hip_bfloat16 *hs1;                           // [S][B][H] (MALL: L0 -> L1)
  __hip_bfloat16 *hs2;                           // [S][B][H] (plain, -> gemm_out)
  float *fin;                                    // out + OUT_ELEMS
  unsigned int *flag0, *flag1;                   // 64 uints each
};

template<int LAY>
__device__ __forceinline__ void run_layer(const R2Args& a, int sub, int tid) {
  __shared__ f32x4 part[4][4][64];
  const int wid = tid >> 6, lane = tid & 63;
  const int col = lane & 15, kl = (lane >> 4) * 8;
  constexpr int K1 = LAY ? H_ : I_;     // W1 inner dim
  constexpr int NX = K1 / 128;          // x-pass chunks per wave (8 or 2)

  unsigned int* mf = LAY ? a.flag1 : a.flag0;
  __hip_bfloat16* hb  = LAY ? a.hb1  : a.hb0;
  __hip_bfloat16* hrb = LAY ? a.hrb1 : a.hrb0;
  const __hip_bfloat16* W2 = LAY ? a.w2_1 : a.w2_0;
  const __hip_bfloat16* W1 = LAY ? a.w1_1 : a.w1_0;
  const __hip_bfloat16* xsrc = LAY ? a.hs1 : a.xb;   // [S][B][K1]

  // ---- weights into VGPRs ----
  bf16x8 wz2[8], wr2[8], wg2[8], wz1[NX], wr1[NX], wg1[NX];
  {
    const __hip_bfloat16* wp = W2 + (size_t)(sub*16+col)*H_ + wid*256 + kl;
#pragma unroll
    for (int kc = 0; kc < 8; ++kc) {
      wz2[kc] = *(const bf16x8*)(wp + kc*32);
      wr2[kc] = *(const bf16x8*)(wp + (size_t)H_*H_   + kc*32);
      wg2[kc] = *(const bf16x8*)(wp + (size_t)2*H_*H_ + kc*32);
    }
    const __hip_bfloat16* qp = W1 + (size_t)(sub*16+col)*K1 + wid*(K1/4) + kl;
#pragma unroll
    for (int c = 0; c < NX; ++c) {
      wz1[c] = *(const bf16x8*)(qp + c*32);
      wr1[c] = *(const bf16x8*)(qp + (size_t)H_*K1   + c*32);
      wg1[c] = *(const bf16x8*)(qp + (size_t)2*H_*K1 + c*32);
    }
  }

  // ---- persistent state (epilogue threads wid<2) ----
  const int b   = wid*16 + (lane & 15);
  const int hh0 = sub*16 + (lane >> 4)*4;
  float hreg[4] = {0,0,0,0}, zreg[4] = {0,0,0,0};
  f32x4 bz4 = {0,0,0,0}, br4 = {0,0,0,0}, bg4 = {0,0,0,0};
  if (wid < 2) {
    bz4 = *(const f32x4*)((LAY ? a.bz1 : a.bz0) + hh0);
    br4 = *(const f32x4*)((LAY ? a.br1 : a.br0) + hh0);
    bg4 = *(const f32x4*)((LAY ? a.bg1 : a.bg0) + hh0);
    f32x4 h4 = *(const f32x4*)(a.h0 + (size_t)b*2048 + LAY*1024 + hh0);
#pragma unroll
    for (int j = 0; j < 4; ++j) hreg[j] = h4[j];
  }
  if (tid < 128) {   // init global bf16 h mirror for this block's slice
    int bb = tid >> 2, hi = sub*16 + (tid & 3)*4;
    f32x4 v = *(const f32x4*)(a.h0 + (size_t)bb*2048 + LAY*1024 + hi);
    u64 pk = 0;
#pragma unroll
    for (int j = 0; j < 4; ++j) pk |= (u64)f2bf(v[j]) << (16*j);
    astore(&hb[(size_t)bb*H_ + hi], pk);
  }
  __syncthreads();
  if (tid == 0) astore32(&mf[sub], 1u);

  for (int t = 0; t < S_; ++t) {
    // ---- waits: own h ready; L1 also needs hs1[t] from L0 ----
    if (wid == 0) {
      unsigned int tgt = 2*t + 1;
      while (aload32(&mf[lane]) < tgt) __builtin_amdgcn_s_sleep(1);
    } else if (LAY == 1 && wid == 1) {
      unsigned int tgt = 2*t + 3;
      while (aload32(&a.flag0[lane]) < tgt) __builtin_amdgcn_s_sleep(1);
    }
    __syncthreads();

    // ---- phase A: z,r = W1*x_t + W2*h (+bias) ----
    bf16x8 xs0[NX], xs1[NX];
    f32x4 az0 = {0,0,0,0}, az1 = {0,0,0,0}, ar0 = {0,0,0,0}, ar1 = {0,0,0,0};
    {
      const __hip_bfloat16* p0 = xsrc + (size_t)t*(B_*K1) + (size_t)col*K1 + wid*(K1/4) + kl;
      const __hip_bfloat16* p1 = p0 + (size_t)16*K1;
#pragma unroll
      for (int c = 0; c < NX; ++c) {
        if (LAY == 0) {                 // plain cacheable (read-only input)
          xs0[c] = *(const bf16x8*)(p0 + c*32);
          xs1[c] = *(const bf16x8*)(p1 + c*32);
        } else {                        // MALL (written by L0 this dispatch)
          U16x8 u0, u1;
          u0.q[0] = aload(p0 + c*32); u0.q[1] = aload(p0 + c*32 + 4);
          u1.q[0] = aload(p1 + c*32); u1.q[1] = aload(p1 + c*32 + 4);
          xs0[c] = u0.v; xs1[c] = u1.v;
        }
        az0 = MFMA16(wz1[c], xs0[c], az0);
        az1 = MFMA16(wz1[c], xs1[c], az1);
        ar0 = MFMA16(wr1[c], xs0[c], ar0);
        ar1 = MFMA16(wr1[c], xs1[c], ar1);
      }
    }
    {
      const __hip_bfloat16* hp0 = hb + (size_t)col*H_ + wid*256 + kl;
      const __hip_bfloat16* hp1 = hp0 + (size_t)16*H_;
#pragma unroll
      for (int kc = 0; kc < 8; ++kc) {
        U16x8 u0, u1;
        u0.q[0] = aload(hp0 + kc*32); u0.q[1] = aload(hp0 + kc*32 + 4);
        u1.q[0] = aload(hp1 + kc*32); u1.q[1] = aload(hp1 + kc*32 + 4);
        az0 = MFMA16(wz2[kc], u0.v, az0);
        az1 = MFMA16(wz2[kc], u1.v, az1);
        ar0 = MFMA16(wr2[kc], u0.v, ar0);
        ar1 = MFMA16(wr2[kc], u1.v, ar1);
      }
    }
    part[wid][0][lane] = az0; part[wid][1][lane] = az1;
    part[wid][2][lane] = ar0; part[wid][3][lane] = ar1;
    __syncthreads();
    if (wid < 2) {
      f32x4 zs = part[0][wid][lane] + part[1][wid][lane] + part[2][wid][lane] + part[3][wid][lane];
      f32x4 rs = part[0][2+wid][lane] + part[1][2+wid][lane] + part[2][2+wid][lane] + part[3][2+wid][lane];
      u64 pk = 0;
#pragma unroll
      for (int j = 0; j < 4; ++j) {
        float z = 1.f / (1.f + __expf(-(zs[j] + bz4[j])));
        float r = 1.f / (1.f + __expf(-(rs[j] + br4[j])));
        zreg[j] = z;
        pk |= (u64)f2bf(r * hreg[j]) << (16*j);
      }
      astore(&hrb[(size_t)b*H_ + hh0], pk);
    }
    __syncthreads();
    if (tid == 0) astore32(&mf[sub], 2*t + 2);
    if (wid == 0) {
      unsigned int tgt = 2*t + 2;
      while (aload32(&mf[lane]) < tgt) __builtin_amdgcn_s_sleep(1);
    }
    __syncthreads();

    // ---- phase B: g = W1g*x_t + W2g*(r.h); h update ----
    f32x4 ag0 = {0,0,0,0}, ag1 = {0,0,0,0};
#pragma unroll
    for (int c = 0; c < NX; ++c) {
      ag0 = MFMA16(wg1[c], xs0[c], ag0);
      ag1 = MFMA16(wg1[c], xs1[c], ag1);
    }
    {
      const __hip_bfloat16* hp0 = hrb + (size_t)col*H_ + wid*256 + kl;
      const __hip_bfloat16* hp1 = hp0 + (size_t)16*H_;
#pragma unroll
      for (int kc = 0; kc < 8; ++kc) {
        U16x8 u0, u1;
        u0.q[0] = aload(hp0 + kc*32); u0.q[1] = aload(hp0 + kc*32 + 4);
        u1.q[0] = aload(hp1 + kc*32); u1.q[1] = aload(hp1 + kc*32 + 4);
        ag0 = MFMA16(wg2[kc], u0.v, ag0);
        ag1 = MFMA16(wg2[kc], u1.v, ag1);
      }
    }
    part[wid][0][lane] = ag0; part[wid][1][lane] = ag1;
    __syncthreads();
    if (wid < 2) {
      f32x4 gs = part[0][wid][lane] + part[1][wid][lane] + part[2][wid][lane] + part[3][wid][lane];
      u64 pk = 0; f32x4 fv;
#pragma unroll
      for (int j = 0; j < 4; ++j) {
        float g  = tanhf(gs[j] + bg4[j]);
        float hn = zreg[j]*hreg[j] + (1.f - zreg[j])*g;
        hreg[j] = hn; fv[j] = hn;
        pk |= (u64)f2bf(hn) << (16*j);
      }
      astore(&hb[(size_t)b*H_ + hh0], pk);
      if (LAY == 0) astore(&a.hs1[((size_t)t*B_ + b)*H_ + hh0], pk);  // MALL -> L1
      else *(u64*)(void*)(a.hs2 + ((size_t)t*B_ + b)*H_ + hh0) = pk;  // plain -> gemm
      if (t == S_-2) *(f32x4*)(a.fin + LAY*1024 + (size_t)b*2048 + hh0) = fv;
    }
    __syncthreads();
    if (tid == 0) astore32(&mf[sub], 2*t + 3);
  }
}

__global__ __launch_bounds__(256, 1) void recur2(R2Args a) {
  const int lay = blockIdx.x >> 6, sub = blockIdx.x & 63;
  if (lay == 0) run_layer<0>(a, sub, threadIdx.x);
  else          run_layer<1>(a, sub, threadIdx.x);
}

// ---------------- host ----------------
extern "C" void kernel_launch(void* const* d_in, const int* in_sizes, int n_in,
                              void* d_out, int out_size, void* d_ws, size_t ws_size,
                              hipStream_t stream) {
  (void)in_sizes; (void)n_in; (void)out_size; (void)ws_size;
  const float* x     = (const float*)d_in[0];
  const float* hid0  = (const float*)d_in[1];
  const float* z1_0  = (const float*)d_in[2];
  const float* z2_0  = (const float*)d_in[3];
  const float* z2b_0 = (const float*)d_in[4];
  const float* r1_0  = (const float*)d_in[5];
  const float* r2_0  = (const float*)d_in[6];
  const float* r2b_0 = (const float*)d_in[7];
  const float* g1_0  = (const float*)d_in[8];
  const float* g2_0  = (const float*)d_in[9];
  const float* g2b_0 = (const float*)d_in[10];
  const float* z1_1  = (const float*)d_in[11];
  const float* z2_1  = (const float*)d_in[12];
  const float* z2b_1 = (const float*)d_in[13];
  const float* r1_1  = (const float*)d_in[14];
  const float* r2_1  = (const float*)d_in[15];
  const float* r2b_1 = (const float*)d_in[16];
  const float* g1_1  = (const float*)d_in[17];
  const float* g2_1  = (const float*)d_in[18];
  const float* g2b_1 = (const float*)d_in[19];
  const float* Yw    = (const float*)d_in[20];
  const float* Yb    = (const float*)d_in[21];
  float* out = (float*)d_out;

  char* ws = (char*)d_ws;
  size_t off = 0;
  auto alloc = [&](size_t bytes) -> void* {
    void* p = ws + off; off += (bytes + 255) & ~(size_t)255; return p;
  };
  __hip_bfloat16* hs1   = (__hip_bfloat16*)alloc((size_t)M_*H_*2);    // 32 MB
  __hip_bfloat16* hs2   = (__hip_bfloat16*)alloc((size_t)M_*H_*2);    // 32 MB
  __hip_bfloat16* xb    = (__hip_bfloat16*)alloc((size_t)M_*I_*2);    // 8 MB
  __hip_bfloat16* w1p0  = (__hip_bfloat16*)alloc((size_t)3*H_*I_*2);
  __hip_bfloat16* w1p1  = (__hip_bfloat16*)alloc((size_t)3*H_*H_*2);
  __hip_bfloat16* w2p0  = (__hip_bfloat16*)alloc((size_t)3*H_*H_*2);
  __hip_bfloat16* w2p1  = (__hip_bfloat16*)alloc((size_t)3*H_*H_*2);
  __hip_bfloat16* ywp   = (__hip_bfloat16*)alloc((size_t)O_*H_*2);
  __hip_bfloat16* hb0   = (__hip_bfloat16*)alloc((size_t)B_*H_*2);
  __hip_bfloat16* hrb0  = (__hip_bfloat16*)alloc((size_t)B_*H_*2);
  __hip_bfloat16* hb1   = (__hip_bfloat16*)alloc((size_t)B_*H_*2);
  __hip_bfloat16* hrb1  = (__hip_bfloat16*)alloc((size_t)B_*H_*2);
  unsigned int*   bars  = (unsigned int*)  alloc(2048);   // flag0 @0, flag1 @+256 uints

  hipMemsetAsync(bars, 0, 2048, stream);

  hipLaunchKernelGGL(xpose_x, dim3(2048), dim3(256), 0, stream, x, xb);
  auto CVT = [&](const float* s, __hip_bfloat16* d, int n) {
    hipLaunchKernelGGL(cvt_f32_bf16, dim3(512), dim3(256), 0, stream, s, d, n);
  };
  CVT(z1_0, w1p0,            H_*I_);
  CVT(r1_0, w1p0 + H_*I_,    H_*I_);
  CVT(g1_0, w1p0 + 2*H_*I_,  H_*I_);
  CVT(z2_0, w2p0,            H_*H_);
  CVT(r2_0, w2p0 + H_*H_,    H_*H_);
  CVT(g2_0, w2p0 + 2*H_*H_,  H_*H_);
  CVT(z1_1, w1p1,            H_*H_);
  CVT(r1_1, w1p1 + H_*H_,    H_*H_);
  CVT(g1_1, w1p1 + 2*H_*H_,  H_*H_);
  CVT(z2_1, w2p1,            H_*H_);
  CVT(r2_1, w2p1 + H_*H_,    H_*H_);
  CVT(g2_1, w2p1 + 2*H_*H_,  H_*H_);
  CVT(Yw,   ywp,             O_*H_);

  R2Args ra;
  ra.xb = xb;
  ra.w1_0 = w1p0; ra.w2_0 = w2p0; ra.w1_1 = w1p1; ra.w2_1 = w2p1;
  ra.bz0 = z2b_0; ra.br0 = r2b_0; ra.bg0 = g2b_0;
  ra.bz1 = z2b_1; ra.br1 = r2b_1; ra.bg1 = g2b_1;
  ra.h0 = hid0;
  ra.hb0 = hb0; ra.hrb0 = hrb0; ra.hb1 = hb1; ra.hrb1 = hrb1;
  ra.hs1 = hs1; ra.hs2 = hs2;
  ra.fin = out + OUT_ELEMS;
  ra.flag0 = bars; ra.flag1 = bars + 256;
  hipLaunchKernelGGL(recur2, dim3(128), dim3(256), 0, stream, ra);

  // output projection + bias
  hipLaunchKernelGGL(gemm_out, dim3(4, 128), dim3(256), 0, stream,
                     hs2, ywp, out, Yb);
}

// Round 8
// 6619.833 us; speedup vs baseline: 10.5434x; 1.5080x over previous
//
#include <hip/hip_runtime.h>
#include <hip/hip_bf16.h>

typedef __bf16 bf16x8 __attribute__((ext_vector_type(8)));
typedef float  f32x4  __attribute__((ext_vector_type(4)));
typedef int    i32x4  __attribute__((ext_vector_type(4)));
typedef unsigned long long u64;

#define B_ 32
#define S_ 512
#define I_ 256
#define H_ 1024
#define O_ 256
#define M_ (B_*S_)   // 16384
#define OUT_ELEMS ((size_t)B_*S_*O_)   // 4194304

#define MFMA16(A,Bf,C) __builtin_amdgcn_mfma_f32_16x16x32_bf16(A,Bf,C,0,0,0)

union V4 { i32x4 i; bf16x8 b; };

// coherent (L2-bypass, agent-visible) bulk loads: 8 x dwordx4, stride 64B,
// issued in one burst, NO wait here (batch waits via WAITV below).
#define LD8(P, V) asm volatile( \
  "global_load_dwordx4 %0, %8, off sc1\n\t" \
  "global_load_dwordx4 %1, %8, off offset:64 sc1\n\t" \
  "global_load_dwordx4 %2, %8, off offset:128 sc1\n\t" \
  "global_load_dwordx4 %3, %8, off offset:192 sc1\n\t" \
  "global_load_dwordx4 %4, %8, off offset:256 sc1\n\t" \
  "global_load_dwordx4 %5, %8, off offset:320 sc1\n\t" \
  "global_load_dwordx4 %6, %8, off offset:384 sc1\n\t" \
  "global_load_dwordx4 %7, %8, off offset:448 sc1" \
  : "=&v"((V)[0].i),"=&v"((V)[1].i),"=&v"((V)[2].i),"=&v"((V)[3].i), \
    "=&v"((V)[4].i),"=&v"((V)[5].i),"=&v"((V)[6].i),"=&v"((V)[7].i) \
  : "v"(P) : "memory")

// wait for ALL outstanding loads, and fence the scheduler so no consumer
// (register-only MFMA) is hoisted above the wait (learn_hip rule #18).
#define WAITV() do { \
  asm volatile("s_waitcnt vmcnt(0)" ::: "memory"); \
  __builtin_amdgcn_sched_barrier(0); \
} while (0)

// agent-scope relaxed atomics (stores + flags; known-correct path).
__device__ __forceinline__ void astore(__hip_bfloat16* p, u64 v) {
  __hip_atomic_store((u64*)p, v, __ATOMIC_RELAXED, __HIP_MEMORY_SCOPE_AGENT);
}
__device__ __forceinline__ unsigned int aload32(const unsigned int* p) {
  return __hip_atomic_load(p, __ATOMIC_RELAXED, __HIP_MEMORY_SCOPE_AGENT);
}
__device__ __forceinline__ void astore32(unsigned int* p, unsigned int v) {
  __hip_atomic_store(p, v, __ATOMIC_RELAXED, __HIP_MEMORY_SCOPE_AGENT);
}
__device__ __forceinline__ unsigned short f2bf(float f) {
  __hip_bfloat16 h = __float2bfloat16(f);
  unsigned short s; __builtin_memcpy(&s, &h, 2); return s;
}

// ---------------- elementwise converts ----------------
__global__ void cvt_f32_bf16(const float* __restrict__ src, __hip_bfloat16* __restrict__ dst, int n) {
  for (int i = blockIdx.x*blockDim.x + threadIdx.x; i < n; i += gridDim.x*blockDim.x)
    dst[i] = __float2bfloat16(src[i]);
}

// x [B][S][I] f32 -> xb [S][B][I] bf16
__global__ void xpose_x(const float* __restrict__ x, __hip_bfloat16* __restrict__ xb) {
  const int total = B_*S_*I_;
  for (int d = blockIdx.x*blockDim.x + threadIdx.x; d < total; d += gridDim.x*blockDim.x) {
    int i = d & (I_-1);
    int b = (d >> 8) & (B_-1);
    int s = d >> 13;
    xb[d] = __float2bfloat16(x[((size_t)b*S_ + s)*I_ + i]);
  }
}

// ---------------- output GEMM: out[(b*S+s)*O+n] = hs2[m]*Yw^T + Yb ----------------
__global__ __launch_bounds__(256) void gemm_out(
    const __hip_bfloat16* __restrict__ A,   // [M][H] = hs2
    const __hip_bfloat16* __restrict__ W,   // [O][H]
    float* __restrict__ dstf,
    const float* __restrict__ bias)
{
  __shared__ __hip_bfloat16 As[128][32];
  __shared__ __hip_bfloat16 Ws[64][32];
  const int tid  = threadIdx.x;
  const int wid  = tid >> 6, lane = tid & 63;
  const int m0   = blockIdx.y * 128, n0 = blockIdx.x * 64;
  const int col  = lane & 15, kl = (lane >> 4) * 8;
  const int lrow = tid >> 2, lcol = (tid & 3) * 8;
  f32x4 acc[2][4] = {};

  for (int k0 = 0; k0 < H_; k0 += 32) {
    __syncthreads();
    *(bf16x8*)&As[lrow][lcol]    = *(const bf16x8*)&A[(size_t)(m0+lrow)*H_    + k0 + lcol];
    *(bf16x8*)&As[lrow+64][lcol] = *(const bf16x8*)&A[(size_t)(m0+lrow+64)*H_ + k0 + lcol];
    *(bf16x8*)&Ws[lrow][lcol]    = *(const bf16x8*)&W[(size_t)(n0+lrow)*H_    + k0 + lcol];
    __syncthreads();
    bf16x8 a0 = *(const bf16x8*)&As[wid*32 + col][kl];
    bf16x8 a1 = *(const bf16x8*)&As[wid*32 + 16 + col][kl];
#pragma unroll
    for (int nt = 0; nt < 4; ++nt) {
      bf16x8 bw = *(const bf16x8*)&Ws[nt*16 + col][kl];
      acc[0][nt] = MFMA16(a0, bw, acc[0][nt]);
      acc[1][nt] = MFMA16(a1, bw, acc[1][nt]);
    }
  }
#pragma unroll
  for (int mt = 0; mt < 2; ++mt)
#pragma unroll
    for (int nt = 0; nt < 4; ++nt)
#pragma unroll
      for (int j = 0; j < 4; ++j) {
        int m = m0 + wid*32 + mt*16 + (lane>>4)*4 + j;
        int n = n0 + nt*16 + col;
        int s = m >> 5, b = m & 31;
        dstf[((size_t)b*S_ + s)*O_ + n] = acc[mt][nt][j] + bias[n];
      }
}

// ---------------- fused 2-layer persistent recurrence ----------------
// Blocks 0..63 = layer 0, 64..127 = layer 1 (pipelined one step behind; L1
// consumes hs1[t] coherently). Input projections fused (W1 in VGPRs).
// Flags: block stores epoch to flag[sub]; wave0 lanes poll one flag each.
// Epochs: init=1, phase A of step t -> 2t+2, phase B -> 2t+3.
struct R2Args {
  const __hip_bfloat16 *xb;                      // [S][B][I]
  const __hip_bfloat16 *w1_0, *w2_0, *w1_1, *w2_1;
  const float *bz0,*br0,*bg0,*bz1,*br1,*bg1;
  const float *h0;                               // [B][2][H]
  __hip_bfloat16 *hb0,*hrb0,*hb1,*hrb1;          // [B][H] (coherent-only)
  __hip_bfloat16 *hs1;                           // [S][B][H] (coherent: L0->L1)
  __hip_bfloat16 *hs2;                           // [S][B][H] (plain, -> gemm_out)
  float *fin;                                    // out + OUT_ELEMS
  unsigned int *flag0, *flag1;                   // 64 uints each
};

template<int LAY>
__device__ __forceinline__ void run_layer(const R2Args& a, int sub, int tid) {
  __shared__ f32x4 part[4][4][64];
  const int wid = tid >> 6, lane = tid & 63;
  const int col = lane & 15, kl = (lane >> 4) * 8;
  constexpr int K1 = LAY ? H_ : I_;     // W1 inner dim
  constexpr int NX = K1 / 128;          // x chunks per wave (8 or 2)

  unsigned int* mf = LAY ? a.flag1 : a.flag0;
  __hip_bfloat16* hb  = LAY ? a.hb1  : a.hb0;
  __hip_bfloat16* hrb = LAY ? a.hrb1 : a.hrb0;
  const __hip_bfloat16* W2 = LAY ? a.w2_1 : a.w2_0;
  const __hip_bfloat16* W1 = LAY ? a.w1_1 : a.w1_0;
  const __hip_bfloat16* xsrc = LAY ? a.hs1 : a.xb;   // [S][B][K1]

  // ---- weights into VGPRs (plain cached; written by earlier dispatches) ----
  bf16x8 wz2[8], wr2[8], wg2[8], wz1[NX], wr1[NX], wg1[NX];
  {
    const __hip_bfloat16* wp = W2 + (size_t)(sub*16+col)*H_ + wid*256 + kl;
#pragma unroll
    for (int kc = 0; kc < 8; ++kc) {
      wz2[kc] = *(const bf16x8*)(wp + kc*32);
      wr2[kc] = *(const bf16x8*)(wp + (size_t)H_*H_   + kc*32);
      wg2[kc] = *(const bf16x8*)(wp + (size_t)2*H_*H_ + kc*32);
    }
    const __hip_bfloat16* qp = W1 + (size_t)(sub*16+col)*K1 + wid*(K1/4) + kl;
#pragma unroll
    for (int c = 0; c < NX; ++c) {
      wz1[c] = *(const bf16x8*)(qp + c*32);
      wr1[c] = *(const bf16x8*)(qp + (size_t)H_*K1   + c*32);
      wg1[c] = *(const bf16x8*)(qp + (size_t)2*H_*K1 + c*32);
    }
  }

  // ---- persistent state (epilogue threads wid<2) ----
  const int b   = wid*16 + (lane & 15);
  const int hh0 = sub*16 + (lane >> 4)*4;
  float hreg[4] = {0,0,0,0}, zreg[4] = {0,0,0,0};
  f32x4 bz4 = {0,0,0,0}, br4 = {0,0,0,0}, bg4 = {0,0,0,0};
  if (wid < 2) {
    bz4 = *(const f32x4*)((LAY ? a.bz1 : a.bz0) + hh0);
    br4 = *(const f32x4*)((LAY ? a.br1 : a.br0) + hh0);
    bg4 = *(const f32x4*)((LAY ? a.bg1 : a.bg0) + hh0);
    f32x4 h4 = *(const f32x4*)(a.h0 + (size_t)b*2048 + LAY*1024 + hh0);
#pragma unroll
    for (int j = 0; j < 4; ++j) hreg[j] = h4[j];
  }
  if (tid < 128) {   // init global bf16 h mirror for this block's slice
    int bb = tid >> 2, hi = sub*16 + (tid & 3)*4;
    f32x4 v = *(const f32x4*)(a.h0 + (size_t)bb*2048 + LAY*1024 + hi);
    u64 pk = 0;
#pragma unroll
    for (int j = 0; j < 4; ++j) pk |= (u64)f2bf(v[j]) << (16*j);
    astore(&hb[(size_t)bb*H_ + hi], pk);
  }
  __syncthreads();
  if (tid == 0) astore32(&mf[sub], 1u);

  for (int t = 0; t < S_; ++t) {
    f32x4 az0 = {0,0,0,0}, az1 = {0,0,0,0};
    f32x4 ar0 = {0,0,0,0}, ar1 = {0,0,0,0};
    f32x4 ag0 = {0,0,0,0}, ag1 = {0,0,0,0};

    // ---- L0: x-pass entirely before the wait (input always ready) ----
    if (LAY == 0) {
      const __hip_bfloat16* p0 = xsrc + (size_t)t*(B_*K1) + (size_t)col*K1 + wid*(K1/4) + kl;
      const __hip_bfloat16* p1 = p0 + (size_t)16*K1;
      bf16x8 xs0[NX], xs1[NX];
#pragma unroll
      for (int c = 0; c < NX; ++c) {
        xs0[c] = *(const bf16x8*)(p0 + c*32);
        xs1[c] = *(const bf16x8*)(p1 + c*32);
      }
#pragma unroll
      for (int c = 0; c < NX; ++c) {
        az0 = MFMA16(wz1[c], xs0[c], az0);  az1 = MFMA16(wz1[c], xs1[c], az1);
        ar0 = MFMA16(wr1[c], xs0[c], ar0);  ar1 = MFMA16(wr1[c], xs1[c], ar1);
        ag0 = MFMA16(wg1[c], xs0[c], ag0);  ag1 = MFMA16(wg1[c], xs1[c], ag1);
      }
    }

    // ---- waits: own h ready; L1 also needs hs1[t] from L0 ----
    if (wid == 0) {
      unsigned int tgt = 2*t + 1;
      while (aload32(&mf[lane]) < tgt) __builtin_amdgcn_s_sleep(1);
    } else if (LAY == 1 && wid == 1) {
      unsigned int tgt = 2*t + 3;
      while (aload32(&a.flag0[lane]) < tgt) __builtin_amdgcn_s_sleep(1);
    }
    __syncthreads();

    // ---- phase A: coherent bulk loads (one latency), then MFMAs ----
    {
      const __hip_bfloat16* hp0 = hb + (size_t)col*H_ + wid*256 + kl;
      const __hip_bfloat16* hp1 = hp0 + (size_t)16*H_;
      V4 HV0[8], HV1[8];
      if (LAY == 1) {
        const __hip_bfloat16* p0 = xsrc + (size_t)t*(B_*K1) + (size_t)col*K1 + wid*(K1/4) + kl;
        const __hip_bfloat16* p1 = p0 + (size_t)16*K1;
        V4 XV0[8], XV1[8];
        LD8(p0, XV0); LD8(p1, XV1);
        LD8(hp0, HV0); LD8(hp1, HV1);
        WAITV();
#pragma unroll
        for (int c = 0; c < 8; ++c) {
          az0 = MFMA16(wz1[c], XV0[c].b, az0);  az1 = MFMA16(wz1[c], XV1[c].b, az1);
          ar0 = MFMA16(wr1[c], XV0[c].b, ar0);  ar1 = MFMA16(wr1[c], XV1[c].b, ar1);
          ag0 = MFMA16(wg1[c], XV0[c].b, ag0);  ag1 = MFMA16(wg1[c], XV1[c].b, ag1);
        }
      } else {
        LD8(hp0, HV0); LD8(hp1, HV1);
        WAITV();
      }
#pragma unroll
      for (int kc = 0; kc < 8; ++kc) {
        az0 = MFMA16(wz2[kc], HV0[kc].b, az0);  az1 = MFMA16(wz2[kc], HV1[kc].b, az1);
        ar0 = MFMA16(wr2[kc], HV0[kc].b, ar0);  ar1 = MFMA16(wr2[kc], HV1[kc].b, ar1);
      }
    }
    part[wid][0][lane] = az0; part[wid][1][lane] = az1;
    part[wid][2][lane] = ar0; part[wid][3][lane] = ar1;
    __syncthreads();
    if (wid < 2) {
      f32x4 zs = part[0][wid][lane] + part[1][wid][lane] + part[2][wid][lane] + part[3][wid][lane];
      f32x4 rs = part[0][2+wid][lane] + part[1][2+wid][lane] + part[2][2+wid][lane] + part[3][2+wid][lane];
      u64 pk = 0;
#pragma unroll
      for (int j = 0; j < 4; ++j) {
        float z = 1.f / (1.f + __expf(-(zs[j] + bz4[j])));
        float r = 1.f / (1.f + __expf(-(rs[j] + br4[j])));
        zreg[j] = z;
        pk |= (u64)f2bf(r * hreg[j]) << (16*j);
      }
      astore(&hrb[(size_t)b*H_ + hh0], pk);
    }
    __syncthreads();
    if (tid == 0) astore32(&mf[sub], 2*t + 2);
    if (wid == 0) {
      unsigned int tgt = 2*t + 2;
      while (aload32(&mf[lane]) < tgt) __builtin_amdgcn_s_sleep(1);
    }
    __syncthreads();

    // ---- phase B: g += W2g*(r.h); h update ----
    {
      const __hip_bfloat16* hp0 = hrb + (size_t)col*H_ + wid*256 + kl;
      const __hip_bfloat16* hp1 = hp0 + (size_t)16*H_;
      V4 RV0[8], RV1[8];
      LD8(hp0, RV0); LD8(hp1, RV1);
      WAITV();
#pragma unroll
      for (int kc = 0; kc < 8; ++kc) {
        ag0 = MFMA16(wg2[kc], RV0[kc].b, ag0);
        ag1 = MFMA16(wg2[kc], RV1[kc].b, ag1);
      }
    }
    part[wid][0][lane] = ag0; part[wid][1][lane] = ag1;
    __syncthreads();
    if (wid < 2) {
      f32x4 gs = part[0][wid][lane] + part[1][wid][lane] + part[2][wid][lane] + part[3][wid][lane];
      u64 pk = 0; f32x4 fv;
#pragma unroll
      for (int j = 0; j < 4; ++j) {
        float g  = tanhf(gs[j] + bg4[j]);
        float hn = zreg[j]*hreg[j] + (1.f - zreg[j])*g;
        hreg[j] = hn; fv[j] = hn;
        pk |= (u64)f2bf(hn) << (16*j);
      }
      astore(&hb[(size_t)b*H_ + hh0], pk);
      if (LAY == 0) astore(&a.hs1[((size_t)t*B_ + b)*H_ + hh0], pk);  // coherent -> L1
      else *(u64*)(void*)(a.hs2 + ((size_t)t*B_ + b)*H_ + hh0) = pk;  // plain -> gemm
      if (t == S_-2) *(f32x4*)(a.fin + LAY*1024 + (size_t)b*2048 + hh0) = fv;
    }
    __syncthreads();
    if (tid == 0) astore32(&mf[sub], 2*t + 3);
  }
}

__global__ __launch_bounds__(256, 1) void recur2(R2Args a) {
  const int lay = blockIdx.x >> 6, sub = blockIdx.x & 63;
  if (lay == 0) run_layer<0>(a, sub, threadIdx.x);
  else          run_layer<1>(a, sub, threadIdx.x);
}

// ---------------- host ----------------
extern "C" void kernel_launch(void* const* d_in, const int* in_sizes, int n_in,
                              void* d_out, int out_size, void* d_ws, size_t ws_size,
                              hipStream_t stream) {
  (void)in_sizes; (void)n_in; (void)out_size; (void)ws_size;
  const float* x     = (const float*)d_in[0];
  const float* hid0  = (const float*)d_in[1];
  const float* z1_0  = (const float*)d_in[2];
  const float* z2_0  = (const float*)d_in[3];
  const float* z2b_0 = (const float*)d_in[4];
  const float* r1_0  = (const float*)d_in[5];
  const float* r2_0  = (const float*)d_in[6];
  const float* r2b_0 = (const float*)d_in[7];
  const float* g1_0  = (const float*)d_in[8];
  const float* g2_0  = (const float*)d_in[9];
  const float* g2b_0 = (const float*)d_in[10];
  const float* z1_1  = (const float*)d_in[11];
  const float* z2_1  = (const float*)d_in[12];
  const float* z2b_1 = (const float*)d_in[13];
  const float* r1_1  = (const float*)d_in[14];
  const float* r2_1  = (const float*)d_in[15];
  const float* r2b_1 = (const float*)d_in[16];
  const float* g1_1  = (const float*)d_in[17];
  const float* g2_1  = (const float*)d_in[18];
  const float* g2b_1 = (const float*)d_in[19];
  const float* Yw    = (const float*)d_in[20];
  const float* Yb    = (const float*)d_in[21];
  float* out = (float*)d_out;

  char* ws = (char*)d_ws;
  size_t off = 0;
  auto alloc = [&](size_t bytes) -> void* {
    void* p = ws + off; off += (bytes + 255) & ~(size_t)255; return p;
  };
  __hip_bfloat16* hs1   = (__hip_bfloat16*)alloc((size_t)M_*H_*2);    // 32 MB
  __hip_bfloat16* hs2   = (__hip_bfloat16*)alloc((size_t)M_*H_*2);    // 32 MB
  __hip_bfloat16* xb    = (__hip_bfloat16*)alloc((size_t)M_*I_*2);    // 8 MB
  __hip_bfloat16* w1p0  = (__hip_bfloat16*)alloc((size_t)3*H_*I_*2);
  __hip_bfloat16* w1p1  = (__hip_bfloat16*)alloc((size_t)3*H_*H_*2);
  __hip_bfloat16* w2p0  = (__hip_bfloat16*)alloc((size_t)3*H_*H_*2);
  __hip_bfloat16* w2p1  = (__hip_bfloat16*)alloc((size_t)3*H_*H_*2);
  __hip_bfloat16* ywp   = (__hip_bfloat16*)alloc((size_t)O_*H_*2);
  __hip_bfloat16* hb0   = (__hip_bfloat16*)alloc((size_t)B_*H_*2);
  __hip_bfloat16* hrb0  = (__hip_bfloat16*)alloc((size_t)B_*H_*2);
  __hip_bfloat16* hb1   = (__hip_bfloat16*)alloc((size_t)B_*H_*2);
  __hip_bfloat16* hrb1  = (__hip_bfloat16*)alloc((size_t)B_*H_*2);
  unsigned int*   bars  = (unsigned int*)  alloc(2048);   // flag0 @0, flag1 @+256 uints

  hipMemsetAsync(bars, 0, 2048, stream);

  hipLaunchKernelGGL(xpose_x, dim3(2048), dim3(256), 0, stream, x, xb);
  auto CVT = [&](const float* s, __hip_bfloat16* d, int n) {
    hipLaunchKernelGGL(cvt_f32_bf16, dim3(512), dim3(256), 0, stream, s, d, n);
  };
  CVT(z1_0, w1p0,            H_*I_);
  CVT(r1_0, w1p0 + H_*I_,    H_*I_);
  CVT(g1_0, w1p0 + 2*H_*I_,  H_*I_);
  CVT(z2_0, w2p0,            H_*H_);
  CVT(r2_0, w2p0 + H_*H_,    H_*H_);
  CVT(g2_0, w2p0 + 2*H_*H_,  H_*H_);
  CVT(z1_1, w1p1,            H_*H_);
  CVT(r1_1, w1p1 + H_*H_,    H_*H_);
  CVT(g1_1, w1p1 + 2*H_*H_,  H_*H_);
  CVT(z2_1, w2p1,            H_*H_);
  CVT(r2_1, w2p1 + H_*H_,    H_*H_);
  CVT(g2_1, w2p1 + 2*H_*H_,  H_*H_);
  CVT(Yw,   ywp,             O_*H_);

  R2Args ra;
  ra.xb = xb;
  ra.w1_0 = w1p0; ra.w2_0 = w2p0; ra.w1_1 = w1p1; ra.w2_1 = w2p1;
  ra.bz0 = z2b_0; ra.br0 = r2b_0; ra.bg0 = g2b_0;
  ra.bz1 = z2b_1; ra.br1 = r2b_1; ra.bg1 = g2b_1;
  ra.h0 = hid0;
  ra.hb0 = hb0; ra.hrb0 = hrb0; ra.hb1 = hb1; ra.hrb1 = hrb1;
  ra.hs1 = hs1; ra.hs2 = hs2;
  ra.fin = out + OUT_ELEMS;
  ra.flag0 = bars; ra.flag1 = bars + 256;
  hipLaunchKernelGGL(recur2, dim3(128), dim3(256), 0, stream, ra);

  // output projection + bias
  hipLaunchKernelGGL(gemm_out, dim3(4, 128), dim3(256), 0, stream,
                     hs2, ywp, out, Yb);
}